// Round 12
// baseline (283.715 us; speedup 1.0000x reference)
//
#include <hip/hip_runtime.h>

// Problem constants
#define B_   16
#define C_   512
#define T_   1024
#define H_   8
#define D_   64
#define G_   32
#define L_   77
#define S_   1101          // T + L
#define SPAD 1152          // padded S (18 tiles of 64)
#define NPAD 51            // SPAD - S_ : zero-pad tokens each add exp2(0)=1 to l
#define CD_  768
#define BT_  (B_*T_)       // 16384
#define SROW 72            // flash epilogue LDS row stride (16B-aligned)
#define QSC  0.18033688011112042f   // 0.125 * log2(e), folded into Q

typedef __bf16 bf16x8 __attribute__((ext_vector_type(8)));
typedef float  f32x4  __attribute__((ext_vector_type(4)));
typedef unsigned int u32x4 __attribute__((ext_vector_type(4)));

static __device__ __forceinline__ unsigned short f2bf(float f) {
    unsigned int u = __float_as_uint(f);
    u = (u + 0x7fffu + ((u >> 16) & 1u)) >> 16;
    return (unsigned short)u;
}

// packed RNE f32x2 -> bf16x2 (single HW instruction)
static __device__ __forceinline__ unsigned int pk_bf16(float a, float b) {
    unsigned int d;
    asm("v_cvt_pk_bf16_f32 %0, %1, %2" : "=v"(d) : "v"(a), "v"(b));
    return d;
}

// R5-R8 lesson (3 failures): EVERY thin path to v_exp_f32 corrupts on this stack
// (raw asm -> NaN; __builtin_amdgcn_exp2f -> absmax 0.156; __expf/native -> 0.135).
// Only the full libm __builtin_exp2f sequence is reliable (0.03125). Do not retry.
static __device__ __forceinline__ float exp2a(float x) {
    return __builtin_exp2f(x);
}

// gfx950 cross-lane swaps (both operands modified):
// swap32: vdst.hi32 <-> vsrc.lo32   => a'={a.lo,b.lo}, b'={a.hi,b.hi}
// swap16: vdst.row1<->vsrc.row0, vdst.row3<->vsrc.row2 (rows = 16 lanes)
static __device__ __forceinline__ void swap32(unsigned& a, unsigned& b) {
    asm volatile("v_permlane32_swap_b32 %0, %1" : "+v"(a), "+v"(b));
}
static __device__ __forceinline__ void swap16(unsigned& a, unsigned& b) {
    asm volatile("v_permlane16_swap_b32 %0, %1" : "+v"(a), "+v"(b));
}

static __device__ __forceinline__ void gload_lds16(const unsigned short* g,
                                                   unsigned short* l) {
    __builtin_amdgcn_global_load_lds(
        (const __attribute__((address_space(1))) unsigned int*)g,
        (__attribute__((address_space(3))) unsigned int*)l, 16, 0, 0);
}

// -------- prep: GN stats (0..511) + weight packing (512..1407) + c pack (1408..1599)
__global__ __launch_bounds__(256) void prep_k(const float* __restrict__ x,
                                              float* __restrict__ stats,
                                              const float* __restrict__ w_qkv,
                                              const float* __restrict__ w_p,
                                              const float* __restrict__ w_c,
                                              const float* __restrict__ cin,
                                              unsigned short* __restrict__ wqkv_pk,
                                              unsigned short* __restrict__ wp_pk,
                                              unsigned short* __restrict__ wc_pk,
                                              unsigned short* __restrict__ cpk) {
    const int tid = threadIdx.x;
    if (blockIdx.x < 512) {
        const int bg = blockIdx.x;
        const float* p = x + (size_t)bg * 16384;
        float s = 0.f, s2 = 0.f;
        for (int i = tid; i < 16384; i += 256) {
            float v = p[i];
            s += v; s2 += v * v;
        }
        __shared__ float rs[256], rs2[256];
        rs[tid] = s; rs2[tid] = s2;
        __syncthreads();
        for (int off = 128; off > 0; off >>= 1) {
            if (tid < off) { rs[tid] += rs[tid + off]; rs2[tid] += rs2[tid + off]; }
            __syncthreads();
        }
        if (tid == 0) {
            float mean = rs[0] * (1.0f / 16384.0f);
            float var  = rs2[0] * (1.0f / 16384.0f) - mean * mean;
            stats[2 * bg]     = mean;
            stats[2 * bg + 1] = rsqrtf(var + 1e-5f);
        }
        return;
    }
    if (blockIdx.x < 1408) {
        const int cid = (blockIdx.x - 512) * 256 + tid;   // 229376 chunks
        const float* src;
        unsigned short* dst;
        if (cid < 98304) {                 // w_qkv 1536x512, KT=8
            const int ml = cid & 127, k8 = (cid >> 7) & 7, kt = (cid >> 10) & 7, mt = cid >> 13;
            src = w_qkv + (size_t)(mt * 128 + ml) * 512 + kt * 64 + k8 * 8;
            dst = wqkv_pk + (size_t)cid * 8;
        } else if (cid < 131072) {         // w_p 512x512, KT=8
            const int c2 = cid - 98304;
            const int ml = c2 & 127, k8 = (c2 >> 7) & 7, kt = (c2 >> 10) & 7, mt = c2 >> 13;
            src = w_p + (size_t)(mt * 128 + ml) * 512 + kt * 64 + k8 * 8;
            dst = wp_pk + (size_t)c2 * 8;
        } else {                           // w_c 1024x768, KT=12
            const int c3 = cid - 131072;
            const int ml = c3 & 127, k8 = (c3 >> 7) & 7;
            const int ktmt = c3 >> 10;
            const int kt = ktmt % 12, mt = ktmt / 12;
            src = w_c + (size_t)(mt * 128 + ml) * 768 + kt * 64 + k8 * 8;
            dst = wc_pk + (size_t)c3 * 8;
        }
        const float4 v0 = *(const float4*)src, v1 = *(const float4*)(src + 4);
        unsigned short tmp[8];
        tmp[0] = f2bf(v0.x); tmp[1] = f2bf(v0.y); tmp[2] = f2bf(v0.z); tmp[3] = f2bf(v0.w);
        tmp[4] = f2bf(v1.x); tmp[5] = f2bf(v1.y); tmp[6] = f2bf(v1.z); tmp[7] = f2bf(v1.w);
        *(uint4*)dst = *(uint4*)tmp;
        return;
    }
    // pack cross input c [b][768][77] -> B layout per batch (KT=12, N padded to 128)
    const int idx2 = blockIdx.x - 1408;     // 192 = 12 kt * 16 b
    const int kt = idx2 % 12, b = idx2 / 12;
#pragma unroll
    for (int it = 0; it < 4; it++) {
        const int idx = it * 256 + tid;     // 1024 chunks per (kt,b)
        const int k8 = idx >> 7, l = idx & 127;
        unsigned short tmp[8];
        const float* src = cin + ((size_t)b * CD_ + kt * 64 + k8 * 8) * L_ + l;
#pragma unroll
        for (int q = 0; q < 8; q++)
            tmp[q] = (l < L_) ? f2bf(src[(size_t)q * L_]) : (unsigned short)0;
        *(uint4*)&cpk[(size_t)b * 98304 + ((size_t)(kt * 8 + k8)) * 1024 + (size_t)l * 8] =
            *(uint4*)tmp;
    }
}

// -------- GroupNorm apply + transpose + bf16 pack into GEMM-B layout --------
__global__ __launch_bounds__(256) void gn_apply_t(const float* __restrict__ x,
                                                  const float* __restrict__ stats,
                                                  const float* __restrict__ gamma,
                                                  const float* __restrict__ beta,
                                                  unsigned short* __restrict__ xnT) {
    const int t0 = blockIdx.x * 64, kt = blockIdx.y, b = blockIdx.z;
    const int c0 = kt * 64;
    const int tid = threadIdx.x;
    __shared__ float st[64][66];   // [t][c]
#pragma unroll
    for (int it = 0; it < 4; it++) {
        const int fid = it * 256 + tid;
        const int ci = fid >> 4, t4 = (fid & 15) * 4;
        const int c = c0 + ci;
        const float4 xv = *(const float4*)&x[((size_t)(b * C_ + c) << 10) + t0 + t4];
        const int bg = b * G_ + (c >> 4);
        const float mean = stats[2 * bg], istd = stats[2 * bg + 1];
        const float gs = gamma[c] * istd, gb = beta[c] - mean * gs;
        st[t4 + 0][ci] = xv.x * gs + gb;
        st[t4 + 1][ci] = xv.y * gs + gb;
        st[t4 + 2][ci] = xv.z * gs + gb;
        st[t4 + 3][ci] = xv.w * gs + gb;
    }
    __syncthreads();
#pragma unroll
    for (int it = 0; it < 2; it++) {
        const int cid = it * 256 + tid;
        const int k8 = cid >> 6, tl = cid & 63;
        const int n = (b << 10) + t0 + tl;
        const int nt = n >> 7, nm = n & 127;
        unsigned short tmp[8];
        const float* src = &st[tl][k8 * 8];
#pragma unroll
        for (int q = 0; q < 8; q++) tmp[q] = f2bf(src[q]);
        *(uint4*)&xnT[(((size_t)nt * 8 + kt) * 8 + k8) * 1024 + (size_t)nm * 8] = *(uint4*)tmp;
    }
}

// ---------------- MFMA bf16 GEMM body, 128x128 tile ----------------
// R11 lesson (occupancy-dependent staging): DIRECT global fragment reads win at
// >=4 blocks/CU (qkvc, 6.5/CU: 74.5->70 µs — zero K-loop barriers, compiler
// pipelines 16 b128 loads over 32 MFMAs, dup reads hit L2 via XCD swizzle) but
// LOSE at 2 blocks/CU (proj: +20 µs — no TLP to hide the un-staged latency).
// DIRECT=0 keeps the R4-proven global_load_lds + 2-barrier loop.
// MODE 0: qkv (KT=8)  -> packed-chunk Q(scaled)/K/V (+bias).
// MODE 1: proj (KT=8) -> fp32 out = C + bias + resid.
// MODE 2: cross (KT=12, batched zz) -> Kc/Vc chunks at stiles 16/17, pad->0.
template<int MODE, int KT, bool DIRECT>
static __device__ __forceinline__ void mgemm_body(const unsigned short* __restrict__ Apk,
                                                  const unsigned short* __restrict__ Bpk,
                                                  const float* __restrict__ bias,
                                                  const float* __restrict__ resid,
                                                  unsigned short* __restrict__ qpk,
                                                  unsigned short* __restrict__ kpk,
                                                  unsigned short* __restrict__ vpk,
                                                  float* __restrict__ outp,
                                                  unsigned short* lds,
                                                  const int nt, const int mt, const int zz) {
    const int tid = threadIdx.x, wave = tid >> 6, lane = tid & 63;
    const int quad = lane >> 4, l16 = lane & 15;
    const int mw = (wave & 1) * 64, nw = (wave >> 1) * 64;

    f32x4 acc[4][4];
#pragma unroll
    for (int i = 0; i < 4; i++)
#pragma unroll
        for (int j = 0; j < 4; j++) acc[i][j] = (f32x4){0.f, 0.f, 0.f, 0.f};

    const unsigned short* Ab = Apk + (size_t)mt * KT * 8192;
    const unsigned short* Bb = Bpk + ((MODE == 2) ? (size_t)zz * KT * 8192 : 0)
                                   + (size_t)nt * KT * 8192;

    if constexpr (DIRECT) {
        // zero-barrier K loop: fragments straight from global (L2-resident panels)
        for (int kt = 0; kt < KT; kt++) {
            const unsigned short* Abase = Ab + kt * 8192;
            const unsigned short* Bbase = Bb + kt * 8192;
#pragma unroll
            for (int kh = 0; kh < 2; kh++) {
                const int k8 = kh * 4 + quad;
                bf16x8 af[4], bfr[4];
#pragma unroll
                for (int i = 0; i < 4; i++) {
                    af[i]  = *(const bf16x8*)&Abase[(size_t)(k8 * 128 + mw + i * 16 + l16) * 8];
                    bfr[i] = *(const bf16x8*)&Bbase[(size_t)(k8 * 128 + nw + i * 16 + l16) * 8];
                }
#pragma unroll
                for (int mi = 0; mi < 4; mi++)
#pragma unroll
                    for (int ni = 0; ni < 4; ni++)
                        acc[mi][ni] = __builtin_amdgcn_mfma_f32_16x16x32_bf16(
                            af[mi], bfr[ni], acc[mi][ni], 0, 0, 0);
            }
        }
    } else {
        // R4-proven staged loop: global_load_lds + 2 barriers per kt
        for (int kt = 0; kt < KT; kt++) {
            const unsigned short* as = Ab + kt * 8192 + wave * 2048 + lane * 8;
            const unsigned short* bs = Bb + kt * 8192 + wave * 2048 + lane * 8;
            unsigned short* la = lds + wave * 2048;
            unsigned short* lb = lds + 8192 + wave * 2048;
#pragma unroll
            for (int j = 0; j < 4; j++) {
                gload_lds16(as + j * 512, la + j * 512);
                gload_lds16(bs + j * 512, lb + j * 512);
            }
            __syncthreads();
#pragma unroll
            for (int kh = 0; kh < 2; kh++) {
                const int k8 = kh * 4 + quad;
                bf16x8 af[4], bfr[4];
#pragma unroll
                for (int i = 0; i < 4; i++) {
                    af[i]  = *(const bf16x8*)&lds[(size_t)(k8 * 128 + mw + i * 16 + l16) * 8];
                    bfr[i] = *(const bf16x8*)&lds[8192 + (size_t)(k8 * 128 + nw + i * 16 + l16) * 8];
                }
#pragma unroll
                for (int mi = 0; mi < 4; mi++)
#pragma unroll
                    for (int ni = 0; ni < 4; ni++)
                        acc[mi][ni] = __builtin_amdgcn_mfma_f32_16x16x32_bf16(
                            af[mi], bfr[ni], acc[mi][ni], 0, 0, 0);
            }
            __syncthreads();
        }
    }

    const int gm0 = mt * 128 + mw;
    const int gn0 = nt * 128 + nw;

    if (MODE == 1) {
        const int b = gn0 >> 10, t0 = gn0 & 1023;
#pragma unroll
        for (int mi = 0; mi < 4; mi++) {
#pragma unroll
            for (int r = 0; r < 4; r++) {
                const int m = gm0 + mi * 16 + quad * 4 + r;
                const float bv = bias[m];
                const size_t rowb = ((size_t)(b * C_ + m) << 10) + t0;
#pragma unroll
                for (int ni = 0; ni < 4; ni++) {
                    const size_t a = rowb + ni * 16 + l16;
                    outp[a] = acc[mi][ni][r] + bv + resid[a];
                }
            }
        }
        return;
    }

    // regions are block-uniform (128-tile never straddles a 512 boundary)
    const int region = gm0 >> 9;              // MODE0: 0=Q 1=K 2=V ; MODE2: 0=Kc 1=Vc
    const int h = (gm0 & 511) >> 6;
    const int b = (MODE == 2) ? zz : (gn0 >> 10);
    const int bh = b * 8 + h;
    const bool vregion = (MODE == 0) ? (region == 2) : (region == 1);

    if (!vregion) {
        // LDS-free packed-chunk writes for Q / K / Kc
        const float sc = (MODE == 0 && region == 0) ? QSC : 1.0f;
        unsigned short* base;
        int trow0;                            // token row base within stile, t64 base
        if (MODE == 0) {
            base = (region == 0) ? qpk + (size_t)bh * 16 * 4096
                                 : kpk + (size_t)bh * 18 * 4096;
            trow0 = gn0 & 1023;
        } else {
            base = kpk + (size_t)(bh * 18 + 16 + (gn0 >> 6)) * 4096;
            trow0 = -1;
        }
#pragma unroll
        for (int mi = 0; mi < 4; mi++) {
            const int k8 = mi * 2 + (quad >> 1);
            const int sub = (quad & 1) * 4;
#pragma unroll
            for (int ni = 0; ni < 4; ni++) {
                float vv[4];
                bool valid = true;
                if (MODE == 2) valid = (gn0 + ni * 16 + l16) < L_;
#pragma unroll
                for (int r = 0; r < 4; r++)
                    vv[r] = valid ? (acc[mi][ni][r] + bias[gm0 + mi * 16 + quad * 4 + r]) * sc
                                  : 0.f;
                uint2 d;
                d.x = pk_bf16(vv[0], vv[1]);
                d.y = pk_bf16(vv[2], vv[3]);
                unsigned short* dst;
                if (MODE == 0) {
                    const int t = trow0 + ni * 16 + l16;
                    dst = base + (size_t)(t >> 6) * 4096 + ((size_t)k8 * 64 + (t & 63)) * 8 + sub;
                } else {
                    const int row = ni * 16 + l16;
                    dst = base + ((size_t)k8 * 64 + row) * 8 + sub;
                }
                *(uint2*)dst = d;
            }
        }
    } else {
        // V: LDS transpose (64x64 XOR-swizzled per-wave slice, R10-verified 0 conflicts)
        unsigned short* wlds = lds + wave * 4096;   // 64 ch x 64 swizzled
        if constexpr (!DIRECT) __syncthreads();     // staging region reuse (already synced)
#pragma unroll
        for (int mi = 0; mi < 4; mi++)
#pragma unroll
            for (int ni = 0; ni < 4; ni++) {
                bool valid = true;
                if (MODE == 2) valid = (gn0 + ni * 16 + l16) < L_;
#pragma unroll
                for (int r = 0; r < 4; r++) {
                    const float v = valid ? acc[mi][ni][r] + bias[gm0 + mi * 16 + quad * 4 + r]
                                          : 0.f;
                    const int t = mi * 16 + quad * 4 + r;          // (t>>2)&3 == quad
                    wlds[(t << 6) + ((ni * 16 + l16) ^ (quad << 4))] = f2bf(v);
                }
            }
        __syncthreads();
        const int stile = (MODE == 0) ? ((gn0 & 1023) >> 6) : (16 + (gn0 >> 6));
        unsigned short* dst = vpk + (size_t)(bh * 18 + stile) * 4096;
        const int sk8 = lane & 7, cb = lane >> 3;
#pragma unroll
        for (int it = 0; it < 8; it++) {
            const int ch = it * 8 + cb;
            *(uint4*)&dst[((size_t)sk8 * 64 + ch) * 8] =
                *(const uint4*)&wlds[(ch << 6) + ((sk8 * 8) ^ (((ch >> 2) & 3) << 4))];
        }
    }
}

// XCD-chunked bijective block swizzle: bid=(y*128+x) -> nt=(bid&7)*16+((bid>>3)&15),
// row=bid>>7. Each XCD gets a 16-wide nt-chunk across all rows -> panels L2-resident.
// qkv (rows 0..11) + cross (row 12) fused; cross hidden under qkv. DIRECT reads
// (6.5 blocks/CU — enough TLP).
__global__ __launch_bounds__(256) void mgemm_qkvc_k(const unsigned short* __restrict__ wqkv_pk,
                                                    const unsigned short* __restrict__ xnT,
                                                    const float* __restrict__ b_qkv,
                                                    const unsigned short* __restrict__ wc_pk,
                                                    const unsigned short* __restrict__ cpk,
                                                    const float* __restrict__ b_c,
                                                    unsigned short* __restrict__ qpk,
                                                    unsigned short* __restrict__ kpk,
                                                    unsigned short* __restrict__ vpk) {
    __shared__ unsigned short lds[16384];   // V-epilogue only (per-wave 4096)
    const int bid = blockIdx.y * 128 + blockIdx.x;
    const int nt  = (bid & 7) * 16 + ((bid >> 3) & 15);
    const int row = bid >> 7;
    if (row < 12) {
        mgemm_body<0, 8, true>(wqkv_pk, xnT, b_qkv, nullptr, qpk, kpk, vpk, nullptr,
                               lds, nt, row, 0);
    } else {
        mgemm_body<2, 12, true>(wc_pk, cpk, b_c, nullptr, nullptr, kpk, vpk, nullptr,
                                lds, 0, nt & 7, nt >> 3);
    }
}

// proj: only 512 blocks = 2 blocks/CU -> DIRECT reads regressed (R11, +20 µs).
// Staged global_load_lds loop (R4-proven at this occupancy).
__global__ __launch_bounds__(256) void mgemm_proj_k(const unsigned short* __restrict__ Apk,
                                                    const unsigned short* __restrict__ Bpk,
                                                    const float* __restrict__ bias,
                                                    const float* __restrict__ resid,
                                                    float* __restrict__ outp) {
    __shared__ unsigned short lds[16384];   // staging A[0,8192) B[8192,16384)
    const int bid = blockIdx.y * 128 + blockIdx.x;
    const int nt  = (bid & 7) * 16 + ((bid >> 3) & 15);
    const int row = bid >> 7;
    mgemm_body<1, 8, false>(Apk, Bpk, bias, resid, nullptr, nullptr, nullptr, outp,
                            lds, nt, row, 0);
}

// ---------------- Flash attention (swapped QK^T, exp2, P in-register, MFMA row-sum) -------
// Grid (bh=128, qt=8). Block: 128 q-tokens, 4 waves x 32 rows (2 B-frag sets).
// K/V double-buffered (issue-early, one barrier/stile). P transpose QK->PV layout done
// in-register via permlane swaps. Softmax denominator l computed on the MFMA pipe —
// l_acc[s] = mfma(ap, ones, l_acc[s]) makes every output column sum_s P[t][s], delivered
// in C-layout directly to the lane that needs linv[t=quad*4+r].
__global__ __launch_bounds__(256, 4) void flash_k(const unsigned short* __restrict__ qpk,
                                                  const unsigned short* __restrict__ kpk,
                                                  const unsigned short* __restrict__ vpk,
                                                  unsigned short* __restrict__ aT) {
    __shared__ __align__(16) unsigned short smem[16384];  // K dbuf [0,8192) V dbuf [8192,16384)

    const int tid  = threadIdx.x;
    const int wave = tid >> 6, lane = tid & 63;
    const int quad = lane >> 4, l16 = lane & 15;
    const int bh  = blockIdx.x;
    const int b = bh >> 3, h = bh & 7;
    const int qt0 = blockIdx.y * 128;

    // Q B-frags for two 16-row sets; wave's tokens = qt0 + wave*32 + set*16 + l16
    const unsigned short* qtb = qpk + ((size_t)bh * 16 + blockIdx.y * 2 + (wave >> 1)) * 4096;
    const int qr0 = (wave & 1) * 32 + l16;
    bf16x8 bq0[2], bq1[2];
#pragma unroll
    for (int s = 0; s < 2; s++) {
        bq0[s] = *(const bf16x8*)&qtb[((size_t)quad * 64 + qr0 + s * 16) * 8];
        bq1[s] = *(const bf16x8*)&qtb[((size_t)(quad + 4) * 64 + qr0 + s * 16) * 8];
    }

    // all-ones bf16 B-fragment for the row-sum MFMA
    union { u32x4 u; bf16x8 v; } one_u;
    one_u.u = (u32x4){0x3F803F80u, 0x3F803F80u, 0x3F803F80u, 0x3F803F80u};
    const bf16x8 vones = one_u.v;

    const unsigned short* kbase = kpk + (size_t)bh * 18 * 4096 + wave * 1024 + lane * 8;
    const unsigned short* vbase = vpk + (size_t)bh * 18 * 4096 + wave * 1024 + lane * 8;

#define STAGE(p, t) do {                                                  \
        const unsigned short* kg = kbase + (size_t)(t) * 4096;            \
        const unsigned short* vg = vbase + (size_t)(t) * 4096;            \
        unsigned short* lkp = smem + (p) * 4096 + wave * 1024;            \
        unsigned short* lvp = smem + 8192 + (p) * 4096 + wave * 1024;     \
        gload_lds16(kg, lkp);       gload_lds16(kg + 512, lkp + 512);     \
        gload_lds16(vg, lvp);       gload_lds16(vg + 512, lvp + 512);     \
    } while (0)

    f32x4 l_acc[2];
    f32x4 o_acc[2][4];
#pragma unroll
    for (int s = 0; s < 2; s++) {
        l_acc[s] = (f32x4){0.f, 0.f, 0.f, 0.f};
#pragma unroll
        for (int nb = 0; nb < 4; nb++) o_acc[s][nb] = (f32x4){0.f, 0.f, 0.f, 0.f};
    }

    STAGE(0, 0);
    __syncthreads();

    for (int t = 0; t < 18; t++) {
        const int p = t & 1;
        if (t < 17) STAGE(p ^ 1, t + 1);   // in flight across tile-t compute
        const unsigned short* kb = smem + p * 4096;
        const unsigned short* vb = smem + 8192 + p * 4096;

        // QK^T: A = K rows (sb*16+l16), B = Q -> sacc[s][sb] = S[t=l16][s=sb*16+quad*4+r]
        f32x4 sacc[2][4];
#pragma unroll
        for (int sb = 0; sb < 4; sb++) {
            const bf16x8 ak0 = *(const bf16x8*)&kb[((size_t)quad * 64 + sb * 16 + l16) * 8];
            const bf16x8 ak1 = *(const bf16x8*)&kb[((size_t)(quad + 4) * 64 + sb * 16 + l16) * 8];
#pragma unroll
            for (int s = 0; s < 2; s++) {
                f32x4 z = (f32x4){0.f, 0.f, 0.f, 0.f};
                z = __builtin_amdgcn_mfma_f32_16x16x32_bf16(ak0, bq0[s], z, 0, 0, 0);
                z = __builtin_amdgcn_mfma_f32_16x16x32_bf16(ak1, bq1[s], z, 0, 0, 0);
                sacc[s][sb] = z;
            }
        }

        // softmax numerator + in-register transpose to PV-A layout.
        bf16x8 ap0[2], ap1[2];
#pragma unroll
        for (int s = 0; s < 2; s++) {
            unsigned w[4][2];
#pragma unroll
            for (int sb = 0; sb < 4; sb++) {
                const float e0 = exp2a(sacc[s][sb][0]);
                const float e1 = exp2a(sacc[s][sb][1]);
                const float e2 = exp2a(sacc[s][sb][2]);
                const float e3 = exp2a(sacc[s][sb][3]);
                w[sb][0] = pk_bf16(e0, e1);
                w[sb][1] = pk_bf16(e2, e3);
            }
            swap32(w[0][0], w[1][0]); swap16(w[0][0], w[1][0]);   // -> P(j0), Q(j0)
            swap32(w[0][1], w[1][1]); swap16(w[0][1], w[1][1]);   // -> P(j1), Q(j1)
            swap32(w[2][0], w[3][0]); swap16(w[2][0], w[3][0]);   // -> R(j0), S(j0)
            swap32(w[2][1], w[3][1]); swap16(w[2][1], w[3][1]);   // -> R(j1), S(j1)
            union { u32x4 u; bf16x8 v; } c0, c1;
            c0.u = (u32x4){w[0][0], w[0][1], w[1][0], w[1][1]};
            c1.u = (u32x4){w[2][0], w[2][1], w[3][0], w[3][1]};
            ap0[s] = c0.v;
            ap1[s] = c1.v;
            // row-sum on the MFMA pipe: lane(q,l) receives l[t=q*4+r] in l_acc[s][r]
            l_acc[s] = __builtin_amdgcn_mfma_f32_16x16x32_bf16(ap0[s], vones, l_acc[s], 0, 0, 0);
            l_acc[s] = __builtin_amdgcn_mfma_f32_16x16x32_bf16(ap1[s], vones, l_acc[s], 0, 0, 0);
        }

        // PV: A = P rows (in-register), B = V chunks; each bv frag feeds both row-sets
#pragma unroll
        for (int nb = 0; nb < 4; nb++) {
            const bf16x8 bv0 = *(const bf16x8*)&vb[((size_t)quad * 64 + nb * 16 + l16) * 8];
            const bf16x8 bv1 = *(const bf16x8*)&vb[((size_t)(quad + 4) * 64 + nb * 16 + l16) * 8];
#pragma unroll
            for (int s = 0; s < 2; s++) {
                o_acc[s][nb] = __builtin_amdgcn_mfma_f32_16x16x32_bf16(ap0[s], bv0, o_acc[s][nb], 0, 0, 0);
                o_acc[s][nb] = __builtin_amdgcn_mfma_f32_16x16x32_bf16(ap1[s], bv1, o_acc[s][nb], 0, 0, 0);
            }
        }
        __syncthreads();   // drains t+1 loads; all waves done with buf[p]
    }
#undef STAGE

    // l for local row quad*4+r is already in l_acc[s][r]; correct for pad tokens
    float linv[2][4];
#pragma unroll
    for (int s = 0; s < 2; s++)
#pragma unroll
        for (int r = 0; r < 4; r++)
            linv[s][r] = 1.0f / (l_acc[s][r] - (float)NPAD);

    // epilogue: O[t=s*16+quad*4+r][ch=nb*16+l16] -> stage [t][ch] in dead K/V LDS
    // -> aT packed-B chunks. Per-wave slice 32x72 shorts (9216 total <= 16384).
    unsigned short* ps = smem + wave * (32 * SROW);
#pragma unroll
    for (int s = 0; s < 2; s++)
#pragma unroll
        for (int nb = 0; nb < 4; nb++)
#pragma unroll
            for (int r = 0; r < 4; r++)
                ps[(s * 16 + quad * 4 + r) * SROW + nb * 16 + l16] =
                    f2bf(o_acc[s][nb][r] * linv[s][r]);
    asm volatile("s_waitcnt lgkmcnt(0)" ::: "memory");
    const int k8 = lane >> 3;
#pragma unroll
    for (int it = 0; it < 4; it++) {
        const int tl = (lane & 7) + it * 8;
        const int n = (b << 10) + qt0 + wave * 32 + tl;
        const int ntb = n >> 7, nm = n & 127;
        *(uint4*)&aT[(((size_t)ntb * 8 + h) * 8 + k8) * 1024 + (size_t)nm * 8] =
            *(const uint4*)&ps[tl * SROW + k8 * 8];
    }
}

// ---------------- Launch ----------------
extern "C" void kernel_launch(void* const* d_in, const int* in_sizes, int n_in,
                              void* d_out, int out_size, void* d_ws, size_t ws_size,
                              hipStream_t stream) {
    const float* x     = (const float*)d_in[0];
    const float* cin   = (const float*)d_in[1];
    const float* gamma = (const float*)d_in[2];
    const float* beta  = (const float*)d_in[3];
    const float* w_qkv = (const float*)d_in[4];
    const float* b_qkv = (const float*)d_in[5];
    const float* w_c   = (const float*)d_in[6];
    const float* b_c   = (const float*)d_in[7];
    const float* w_p   = (const float*)d_in[8];
    const float* b_p   = (const float*)d_in[9];
    float* out = (float*)d_out;

    float* ws    = (float*)d_ws;
    float* stats = ws;                                        // 1,024 f
    unsigned short* xnT     = (unsigned short*)(ws + 1024);   // 8,388,608 us
    unsigned short* wqkv_pk = xnT + 8388608;                  // 786,432 us
    unsigned short* wp_pk   = wqkv_pk + 786432;               // 262,144 us
    unsigned short* wc_pk   = wp_pk + 262144;                 // 786,432 us
    unsigned short* cpk     = wc_pk + 786432;                 // 1,572,864 us
    unsigned short* qpk     = cpk + 1572864;                  // 8,388,608 us
    unsigned short* kpk     = qpk + 8388608;                  // 9,437,184 us
    unsigned short* vpk     = kpk + 9437184;                  // 9,437,184 us
    unsigned short* aT      = vpk + 9437184;                  // 8,388,608 us
    // total ~95 MB

    prep_k<<<dim3(1600), 256, 0, stream>>>(x, stats, w_qkv, w_p, w_c, cin,
                                           wqkv_pk, wp_pk, wc_pk, cpk);
    gn_apply_t<<<dim3(16, 8, 16), 256, 0, stream>>>(x, stats, gamma, beta, xnT);
    // qkv + cross MFMA GEMMs fused -> qpk (scaled) / kpk / vpk (+stiles 16,17)
    mgemm_qkvc_k<<<dim3(128, 13), 256, 0, stream>>>(wqkv_pk, xnT, b_qkv,
                                                    wc_pk, cpk, b_c,
                                                    qpk, kpk, vpk);
    // flash attention -> aT (packed B layout for proj)
    flash_k<<<dim3(128, 8), 256, 0, stream>>>(qpk, kpk, vpk, aT);
    // proj MFMA GEMM + bias + residual -> out
    mgemm_proj_k<<<dim3(128, 4), 256, 0, stream>>>(wp_pk, aT, b_p, x, out);
}

// Round 13
// 281.427 us; speedup vs baseline: 1.0081x; 1.0081x over previous
//
#include <hip/hip_runtime.h>

// Problem constants
#define B_   16
#define C_   512
#define T_   1024
#define H_   8
#define D_   64
#define G_   32
#define L_   77
#define S_   1101          // T + L
#define SPAD 1152          // padded S (18 tiles of 64)
#define NPAD 51            // SPAD - S_ : zero-pad tokens each add exp2(0)=1 to l
#define CD_  768
#define BT_  (B_*T_)       // 16384
#define SROW 72            // flash epilogue LDS row stride (16B-aligned)
#define QSC  0.18033688011112042f   // 0.125 * log2(e), folded into Q

typedef __bf16 bf16x8 __attribute__((ext_vector_type(8)));
typedef float  f32x4  __attribute__((ext_vector_type(4)));
typedef unsigned int u32x4 __attribute__((ext_vector_type(4)));

static __device__ __forceinline__ unsigned short f2bf(float f) {
    unsigned int u = __float_as_uint(f);
    u = (u + 0x7fffu + ((u >> 16) & 1u)) >> 16;
    return (unsigned short)u;
}

// packed RNE f32x2 -> bf16x2 (single HW instruction)
static __device__ __forceinline__ unsigned int pk_bf16(float a, float b) {
    unsigned int d;
    asm("v_cvt_pk_bf16_f32 %0, %1, %2" : "=v"(d) : "v"(a), "v"(b));
    return d;
}

// R5-R8 lesson (3 failures): EVERY thin path to v_exp_f32 corrupts on this stack
// (raw asm -> NaN; __builtin_amdgcn_exp2f -> absmax 0.156; __expf/native -> 0.135).
// Only the full libm __builtin_exp2f sequence is reliable (0.03125). Do not retry.
static __device__ __forceinline__ float exp2a(float x) {
    return __builtin_exp2f(x);
}

// gfx950 cross-lane swaps (both operands modified):
// swap32: vdst.hi32 <-> vsrc.lo32   => a'={a.lo,b.lo}, b'={a.hi,b.hi}
// swap16: vdst.row1<->vsrc.row0, vdst.row3<->vsrc.row2 (rows = 16 lanes)
static __device__ __forceinline__ void swap32(unsigned& a, unsigned& b) {
    asm volatile("v_permlane32_swap_b32 %0, %1" : "+v"(a), "+v"(b));
}
static __device__ __forceinline__ void swap16(unsigned& a, unsigned& b) {
    asm volatile("v_permlane16_swap_b32 %0, %1" : "+v"(a), "+v"(b));
}

static __device__ __forceinline__ void gload_lds16(const unsigned short* g,
                                                   unsigned short* l) {
    __builtin_amdgcn_global_load_lds(
        (const __attribute__((address_space(1))) unsigned int*)g,
        (__attribute__((address_space(3))) unsigned int*)l, 16, 0, 0);
}

// -------- prep: GN stats (0..511) + weight packing (512..1407) + c pack (1408..1599)
__global__ __launch_bounds__(256) void prep_k(const float* __restrict__ x,
                                              float* __restrict__ stats,
                                              const float* __restrict__ w_qkv,
                                              const float* __restrict__ w_p,
                                              const float* __restrict__ w_c,
                                              const float* __restrict__ cin,
                                              unsigned short* __restrict__ wqkv_pk,
                                              unsigned short* __restrict__ wp_pk,
                                              unsigned short* __restrict__ wc_pk,
                                              unsigned short* __restrict__ cpk) {
    const int tid = threadIdx.x;
    if (blockIdx.x < 512) {
        const int bg = blockIdx.x;
        const float* p = x + (size_t)bg * 16384;
        float s = 0.f, s2 = 0.f;
        for (int i = tid; i < 16384; i += 256) {
            float v = p[i];
            s += v; s2 += v * v;
        }
        __shared__ float rs[256], rs2[256];
        rs[tid] = s; rs2[tid] = s2;
        __syncthreads();
        for (int off = 128; off > 0; off >>= 1) {
            if (tid < off) { rs[tid] += rs[tid + off]; rs2[tid] += rs2[tid + off]; }
            __syncthreads();
        }
        if (tid == 0) {
            float mean = rs[0] * (1.0f / 16384.0f);
            float var  = rs2[0] * (1.0f / 16384.0f) - mean * mean;
            stats[2 * bg]     = mean;
            stats[2 * bg + 1] = rsqrtf(var + 1e-5f);
        }
        return;
    }
    if (blockIdx.x < 1408) {
        const int cid = (blockIdx.x - 512) * 256 + tid;   // 229376 chunks
        const float* src;
        unsigned short* dst;
        if (cid < 98304) {                 // w_qkv 1536x512, KT=8
            const int ml = cid & 127, k8 = (cid >> 7) & 7, kt = (cid >> 10) & 7, mt = cid >> 13;
            src = w_qkv + (size_t)(mt * 128 + ml) * 512 + kt * 64 + k8 * 8;
            dst = wqkv_pk + (size_t)cid * 8;
        } else if (cid < 131072) {         // w_p 512x512, KT=8
            const int c2 = cid - 98304;
            const int ml = c2 & 127, k8 = (c2 >> 7) & 7, kt = (c2 >> 10) & 7, mt = c2 >> 13;
            src = w_p + (size_t)(mt * 128 + ml) * 512 + kt * 64 + k8 * 8;
            dst = wp_pk + (size_t)c2 * 8;
        } else {                           // w_c 1024x768, KT=12
            const int c3 = cid - 131072;
            const int ml = c3 & 127, k8 = (c3 >> 7) & 7;
            const int ktmt = c3 >> 10;
            const int kt = ktmt % 12, mt = ktmt / 12;
            src = w_c + (size_t)(mt * 128 + ml) * 768 + kt * 64 + k8 * 8;
            dst = wc_pk + (size_t)c3 * 8;
        }
        const float4 v0 = *(const float4*)src, v1 = *(const float4*)(src + 4);
        unsigned short tmp[8];
        tmp[0] = f2bf(v0.x); tmp[1] = f2bf(v0.y); tmp[2] = f2bf(v0.z); tmp[3] = f2bf(v0.w);
        tmp[4] = f2bf(v1.x); tmp[5] = f2bf(v1.y); tmp[6] = f2bf(v1.z); tmp[7] = f2bf(v1.w);
        *(uint4*)dst = *(uint4*)tmp;
        return;
    }
    // pack cross input c [b][768][77] -> B layout per batch (KT=12, N padded to 128)
    const int idx2 = blockIdx.x - 1408;     // 192 = 12 kt * 16 b
    const int kt = idx2 % 12, b = idx2 / 12;
#pragma unroll
    for (int it = 0; it < 4; it++) {
        const int idx = it * 256 + tid;     // 1024 chunks per (kt,b)
        const int k8 = idx >> 7, l = idx & 127;
        unsigned short tmp[8];
        const float* src = cin + ((size_t)b * CD_ + kt * 64 + k8 * 8) * L_ + l;
#pragma unroll
        for (int q = 0; q < 8; q++)
            tmp[q] = (l < L_) ? f2bf(src[(size_t)q * L_]) : (unsigned short)0;
        *(uint4*)&cpk[(size_t)b * 98304 + ((size_t)(kt * 8 + k8)) * 1024 + (size_t)l * 8] =
            *(uint4*)tmp;
    }
}

// -------- GroupNorm apply + transpose + bf16 pack into GEMM-B layout --------
__global__ __launch_bounds__(256) void gn_apply_t(const float* __restrict__ x,
                                                  const float* __restrict__ stats,
                                                  const float* __restrict__ gamma,
                                                  const float* __restrict__ beta,
                                                  unsigned short* __restrict__ xnT) {
    const int t0 = blockIdx.x * 64, kt = blockIdx.y, b = blockIdx.z;
    const int c0 = kt * 64;
    const int tid = threadIdx.x;
    __shared__ float st[64][66];   // [t][c]
#pragma unroll
    for (int it = 0; it < 4; it++) {
        const int fid = it * 256 + tid;
        const int ci = fid >> 4, t4 = (fid & 15) * 4;
        const int c = c0 + ci;
        const float4 xv = *(const float4*)&x[((size_t)(b * C_ + c) << 10) + t0 + t4];
        const int bg = b * G_ + (c >> 4);
        const float mean = stats[2 * bg], istd = stats[2 * bg + 1];
        const float gs = gamma[c] * istd, gb = beta[c] - mean * gs;
        st[t4 + 0][ci] = xv.x * gs + gb;
        st[t4 + 1][ci] = xv.y * gs + gb;
        st[t4 + 2][ci] = xv.z * gs + gb;
        st[t4 + 3][ci] = xv.w * gs + gb;
    }
    __syncthreads();
#pragma unroll
    for (int it = 0; it < 2; it++) {
        const int cid = it * 256 + tid;
        const int k8 = cid >> 6, tl = cid & 63;
        const int n = (b << 10) + t0 + tl;
        const int nt = n >> 7, nm = n & 127;
        unsigned short tmp[8];
        const float* src = &st[tl][k8 * 8];
#pragma unroll
        for (int q = 0; q < 8; q++) tmp[q] = f2bf(src[q]);
        *(uint4*)&xnT[(((size_t)nt * 8 + kt) * 8 + k8) * 1024 + (size_t)nm * 8] = *(uint4*)tmp;
    }
}

// ---------------- MFMA bf16 GEMM body, 128x128 tile ----------------
// Occupancy-dependent staging (R11): DIRECT global fragment reads win at >=4 blocks/CU
// (qkvc 6.5/CU: zero K-loop barriers, dup reads hit L2). DIRECT=0 keeps the R4-proven
// global_load_lds + 2-barrier loop (proj, 2 blocks/CU).
// R12 lesson: XCD block swizzle HURT proj (~20 µs) — proj is write-stream-bound
// (128 MB out+resid), and the swizzle fragments HBM page locality of concurrent
// writers. Swizzle only where operand reads dominate (qkvc).
// MODE 0: qkv (KT=8)  -> packed-chunk Q(scaled)/K/V (+bias).
// MODE 1: proj (KT=8) -> fp32 out = C + bias + resid.
// MODE 2: cross (KT=12, batched zz) -> Kc/Vc chunks at stiles 16/17, pad->0.
template<int MODE, int KT, bool DIRECT>
static __device__ __forceinline__ void mgemm_body(const unsigned short* __restrict__ Apk,
                                                  const unsigned short* __restrict__ Bpk,
                                                  const float* __restrict__ bias,
                                                  const float* __restrict__ resid,
                                                  unsigned short* __restrict__ qpk,
                                                  unsigned short* __restrict__ kpk,
                                                  unsigned short* __restrict__ vpk,
                                                  float* __restrict__ outp,
                                                  unsigned short* lds,
                                                  const int nt, const int mt, const int zz) {
    const int tid = threadIdx.x, wave = tid >> 6, lane = tid & 63;
    const int quad = lane >> 4, l16 = lane & 15;
    const int mw = (wave & 1) * 64, nw = (wave >> 1) * 64;

    f32x4 acc[4][4];
#pragma unroll
    for (int i = 0; i < 4; i++)
#pragma unroll
        for (int j = 0; j < 4; j++) acc[i][j] = (f32x4){0.f, 0.f, 0.f, 0.f};

    const unsigned short* Ab = Apk + (size_t)mt * KT * 8192;
    const unsigned short* Bb = Bpk + ((MODE == 2) ? (size_t)zz * KT * 8192 : 0)
                                   + (size_t)nt * KT * 8192;

    if constexpr (DIRECT) {
        // zero-barrier K loop: fragments straight from global (L2-resident panels)
        for (int kt = 0; kt < KT; kt++) {
            const unsigned short* Abase = Ab + kt * 8192;
            const unsigned short* Bbase = Bb + kt * 8192;
#pragma unroll
            for (int kh = 0; kh < 2; kh++) {
                const int k8 = kh * 4 + quad;
                bf16x8 af[4], bfr[4];
#pragma unroll
                for (int i = 0; i < 4; i++) {
                    af[i]  = *(const bf16x8*)&Abase[(size_t)(k8 * 128 + mw + i * 16 + l16) * 8];
                    bfr[i] = *(const bf16x8*)&Bbase[(size_t)(k8 * 128 + nw + i * 16 + l16) * 8];
                }
#pragma unroll
                for (int mi = 0; mi < 4; mi++)
#pragma unroll
                    for (int ni = 0; ni < 4; ni++)
                        acc[mi][ni] = __builtin_amdgcn_mfma_f32_16x16x32_bf16(
                            af[mi], bfr[ni], acc[mi][ni], 0, 0, 0);
            }
        }
    } else {
        // R4-proven staged loop: global_load_lds + 2 barriers per kt
        for (int kt = 0; kt < KT; kt++) {
            const unsigned short* as = Ab + kt * 8192 + wave * 2048 + lane * 8;
            const unsigned short* bs = Bb + kt * 8192 + wave * 2048 + lane * 8;
            unsigned short* la = lds + wave * 2048;
            unsigned short* lb = lds + 8192 + wave * 2048;
#pragma unroll
            for (int j = 0; j < 4; j++) {
                gload_lds16(as + j * 512, la + j * 512);
                gload_lds16(bs + j * 512, lb + j * 512);
            }
            __syncthreads();
#pragma unroll
            for (int kh = 0; kh < 2; kh++) {
                const int k8 = kh * 4 + quad;
                bf16x8 af[4], bfr[4];
#pragma unroll
                for (int i = 0; i < 4; i++) {
                    af[i]  = *(const bf16x8*)&lds[(size_t)(k8 * 128 + mw + i * 16 + l16) * 8];
                    bfr[i] = *(const bf16x8*)&lds[8192 + (size_t)(k8 * 128 + nw + i * 16 + l16) * 8];
                }
#pragma unroll
                for (int mi = 0; mi < 4; mi++)
#pragma unroll
                    for (int ni = 0; ni < 4; ni++)
                        acc[mi][ni] = __builtin_amdgcn_mfma_f32_16x16x32_bf16(
                            af[mi], bfr[ni], acc[mi][ni], 0, 0, 0);
            }
            __syncthreads();
        }
    }

    const int gm0 = mt * 128 + mw;
    const int gn0 = nt * 128 + nw;

    if (MODE == 1) {
        const int b = gn0 >> 10, t0 = gn0 & 1023;
#pragma unroll
        for (int mi = 0; mi < 4; mi++) {
#pragma unroll
            for (int r = 0; r < 4; r++) {
                const int m = gm0 + mi * 16 + quad * 4 + r;
                const float bv = bias[m];
                const size_t rowb = ((size_t)(b * C_ + m) << 10) + t0;
#pragma unroll
                for (int ni = 0; ni < 4; ni++) {
                    const size_t a = rowb + ni * 16 + l16;
                    outp[a] = acc[mi][ni][r] + bv + resid[a];
                }
            }
        }
        return;
    }

    // regions are block-uniform (128-tile never straddles a 512 boundary)
    const int region = gm0 >> 9;              // MODE0: 0=Q 1=K 2=V ; MODE2: 0=Kc 1=Vc
    const int h = (gm0 & 511) >> 6;
    const int b = (MODE == 2) ? zz : (gn0 >> 10);
    const int bh = b * 8 + h;
    const bool vregion = (MODE == 0) ? (region == 2) : (region == 1);

    if (!vregion) {
        // LDS-free packed-chunk writes for Q / K / Kc
        const float sc = (MODE == 0 && region == 0) ? QSC : 1.0f;
        unsigned short* base;
        int trow0;                            // token row base within stile, t64 base
        if (MODE == 0) {
            base = (region == 0) ? qpk + (size_t)bh * 16 * 4096
                                 : kpk + (size_t)bh * 18 * 4096;
            trow0 = gn0 & 1023;
        } else {
            base = kpk + (size_t)(bh * 18 + 16 + (gn0 >> 6)) * 4096;
            trow0 = -1;
        }
#pragma unroll
        for (int mi = 0; mi < 4; mi++) {
            const int k8 = mi * 2 + (quad >> 1);
            const int sub = (quad & 1) * 4;
#pragma unroll
            for (int ni = 0; ni < 4; ni++) {
                float vv[4];
                bool valid = true;
                if (MODE == 2) valid = (gn0 + ni * 16 + l16) < L_;
#pragma unroll
                for (int r = 0; r < 4; r++)
                    vv[r] = valid ? (acc[mi][ni][r] + bias[gm0 + mi * 16 + quad * 4 + r]) * sc
                                  : 0.f;
                uint2 d;
                d.x = pk_bf16(vv[0], vv[1]);
                d.y = pk_bf16(vv[2], vv[3]);
                unsigned short* dst;
                if (MODE == 0) {
                    const int t = trow0 + ni * 16 + l16;
                    dst = base + (size_t)(t >> 6) * 4096 + ((size_t)k8 * 64 + (t & 63)) * 8 + sub;
                } else {
                    const int row = ni * 16 + l16;
                    dst = base + ((size_t)k8 * 64 + row) * 8 + sub;
                }
                *(uint2*)dst = d;
            }
        }
    } else {
        // V: LDS transpose (64x64 XOR-swizzled per-wave slice, R10-verified 0 conflicts)
        unsigned short* wlds = lds + wave * 4096;   // 64 ch x 64 swizzled
        if constexpr (!DIRECT) __syncthreads();     // staging region reuse (already synced)
#pragma unroll
        for (int mi = 0; mi < 4; mi++)
#pragma unroll
            for (int ni = 0; ni < 4; ni++) {
                bool valid = true;
                if (MODE == 2) valid = (gn0 + ni * 16 + l16) < L_;
#pragma unroll
                for (int r = 0; r < 4; r++) {
                    const float v = valid ? acc[mi][ni][r] + bias[gm0 + mi * 16 + quad * 4 + r]
                                          : 0.f;
                    const int t = mi * 16 + quad * 4 + r;          // (t>>2)&3 == quad
                    wlds[(t << 6) + ((ni * 16 + l16) ^ (quad << 4))] = f2bf(v);
                }
            }
        __syncthreads();
        const int stile = (MODE == 0) ? ((gn0 & 1023) >> 6) : (16 + (gn0 >> 6));
        unsigned short* dst = vpk + (size_t)(bh * 18 + stile) * 4096;
        const int sk8 = lane & 7, cb = lane >> 3;
#pragma unroll
        for (int it = 0; it < 8; it++) {
            const int ch = it * 8 + cb;
            *(uint4*)&dst[((size_t)sk8 * 64 + ch) * 8] =
                *(const uint4*)&wlds[(ch << 6) + ((sk8 * 8) ^ (((ch >> 2) & 3) << 4))];
        }
    }
}

// XCD-chunked bijective block swizzle (qkvc only — operand reads dominate there):
// bid -> nt=(bid&7)*16+((bid>>3)&15), row=bid>>7. Panels L2-resident per XCD.
// qkv (rows 0..11) + cross (row 12) fused; DIRECT reads (6.5 blocks/CU).
__global__ __launch_bounds__(256) void mgemm_qkvc_k(const unsigned short* __restrict__ wqkv_pk,
                                                    const unsigned short* __restrict__ xnT,
                                                    const float* __restrict__ b_qkv,
                                                    const unsigned short* __restrict__ wc_pk,
                                                    const unsigned short* __restrict__ cpk,
                                                    const float* __restrict__ b_c,
                                                    unsigned short* __restrict__ qpk,
                                                    unsigned short* __restrict__ kpk,
                                                    unsigned short* __restrict__ vpk) {
    __shared__ unsigned short lds[16384];   // V-epilogue only (per-wave 4096)
    const int bid = blockIdx.y * 128 + blockIdx.x;
    const int nt  = (bid & 7) * 16 + ((bid >> 3) & 15);
    const int row = bid >> 7;
    if (row < 12) {
        mgemm_body<0, 8, true>(wqkv_pk, xnT, b_qkv, nullptr, qpk, kpk, vpk, nullptr,
                               lds, nt, row, 0);
    } else {
        mgemm_body<2, 12, true>(wc_pk, cpk, b_c, nullptr, nullptr, kpk, vpk, nullptr,
                                lds, 0, nt & 7, nt >> 3);
    }
}

// proj: R9-exact configuration — staged loop, PLAIN linear block order (no swizzle:
// proj is bound by its 128 MB out+resid stream; R12 showed the swizzle costs ~20 µs
// by fragmenting concurrent writers' HBM page locality).
__global__ __launch_bounds__(256) void mgemm_proj_k(const unsigned short* __restrict__ Apk,
                                                    const unsigned short* __restrict__ Bpk,
                                                    const float* __restrict__ bias,
                                                    const float* __restrict__ resid,
                                                    float* __restrict__ outp) {
    __shared__ unsigned short lds[16384];   // staging A[0,8192) B[8192,16384)
    mgemm_body<1, 8, false>(Apk, Bpk, bias, resid, nullptr, nullptr, nullptr, outp,
                            lds, blockIdx.x, blockIdx.y, 0);
}

// ---------------- Flash attention (swapped QK^T, exp2, P in-register, MFMA row-sum) -------
// Grid (bh=128, qt=8). Block: 128 q-tokens, 4 waves x 32 rows (2 B-frag sets).
// K/V double-buffered (issue-early, one barrier/stile). P transpose QK->PV layout done
// in-register via permlane swaps. Softmax denominator l computed on the MFMA pipe —
// l_acc[s] = mfma(ap, ones, l_acc[s]) makes every output column sum_s P[t][s], delivered
// in C-layout directly to the lane that needs linv[t=quad*4+r].
__global__ __launch_bounds__(256, 4) void flash_k(const unsigned short* __restrict__ qpk,
                                                  const unsigned short* __restrict__ kpk,
                                                  const unsigned short* __restrict__ vpk,
                                                  unsigned short* __restrict__ aT) {
    __shared__ __align__(16) unsigned short smem[16384];  // K dbuf [0,8192) V dbuf [8192,16384)

    const int tid  = threadIdx.x;
    const int wave = tid >> 6, lane = tid & 63;
    const int quad = lane >> 4, l16 = lane & 15;
    const int bh  = blockIdx.x;
    const int b = bh >> 3, h = bh & 7;
    const int qt0 = blockIdx.y * 128;

    // Q B-frags for two 16-row sets; wave's tokens = qt0 + wave*32 + set*16 + l16
    const unsigned short* qtb = qpk + ((size_t)bh * 16 + blockIdx.y * 2 + (wave >> 1)) * 4096;
    const int qr0 = (wave & 1) * 32 + l16;
    bf16x8 bq0[2], bq1[2];
#pragma unroll
    for (int s = 0; s < 2; s++) {
        bq0[s] = *(const bf16x8*)&qtb[((size_t)quad * 64 + qr0 + s * 16) * 8];
        bq1[s] = *(const bf16x8*)&qtb[((size_t)(quad + 4) * 64 + qr0 + s * 16) * 8];
    }

    // all-ones bf16 B-fragment for the row-sum MFMA
    union { u32x4 u; bf16x8 v; } one_u;
    one_u.u = (u32x4){0x3F803F80u, 0x3F803F80u, 0x3F803F80u, 0x3F803F80u};
    const bf16x8 vones = one_u.v;

    const unsigned short* kbase = kpk + (size_t)bh * 18 * 4096 + wave * 1024 + lane * 8;
    const unsigned short* vbase = vpk + (size_t)bh * 18 * 4096 + wave * 1024 + lane * 8;

#define STAGE(p, t) do {                                                  \
        const unsigned short* kg = kbase + (size_t)(t) * 4096;            \
        const unsigned short* vg = vbase + (size_t)(t) * 4096;            \
        unsigned short* lkp = smem + (p) * 4096 + wave * 1024;            \
        unsigned short* lvp = smem + 8192 + (p) * 4096 + wave * 1024;     \
        gload_lds16(kg, lkp);       gload_lds16(kg + 512, lkp + 512);     \
        gload_lds16(vg, lvp);       gload_lds16(vg + 512, lvp + 512);     \
    } while (0)

    f32x4 l_acc[2];
    f32x4 o_acc[2][4];
#pragma unroll
    for (int s = 0; s < 2; s++) {
        l_acc[s] = (f32x4){0.f, 0.f, 0.f, 0.f};
#pragma unroll
        for (int nb = 0; nb < 4; nb++) o_acc[s][nb] = (f32x4){0.f, 0.f, 0.f, 0.f};
    }

    STAGE(0, 0);
    __syncthreads();

    for (int t = 0; t < 18; t++) {
        const int p = t & 1;
        if (t < 17) STAGE(p ^ 1, t + 1);   // in flight across tile-t compute
        const unsigned short* kb = smem + p * 4096;
        const unsigned short* vb = smem + 8192 + p * 4096;

        // QK^T: A = K rows (sb*16+l16), B = Q -> sacc[s][sb] = S[t=l16][s=sb*16+quad*4+r]
        f32x4 sacc[2][4];
#pragma unroll
        for (int sb = 0; sb < 4; sb++) {
            const bf16x8 ak0 = *(const bf16x8*)&kb[((size_t)quad * 64 + sb * 16 + l16) * 8];
            const bf16x8 ak1 = *(const bf16x8*)&kb[((size_t)(quad + 4) * 64 + sb * 16 + l16) * 8];
#pragma unroll
            for (int s = 0; s < 2; s++) {
                f32x4 z = (f32x4){0.f, 0.f, 0.f, 0.f};
                z = __builtin_amdgcn_mfma_f32_16x16x32_bf16(ak0, bq0[s], z, 0, 0, 0);
                z = __builtin_amdgcn_mfma_f32_16x16x32_bf16(ak1, bq1[s], z, 0, 0, 0);
                sacc[s][sb] = z;
            }
        }

        // softmax numerator + in-register transpose to PV-A layout.
        bf16x8 ap0[2], ap1[2];
#pragma unroll
        for (int s = 0; s < 2; s++) {
            unsigned w[4][2];
#pragma unroll
            for (int sb = 0; sb < 4; sb++) {
                const float e0 = exp2a(sacc[s][sb][0]);
                const float e1 = exp2a(sacc[s][sb][1]);
                const float e2 = exp2a(sacc[s][sb][2]);
                const float e3 = exp2a(sacc[s][sb][3]);
                w[sb][0] = pk_bf16(e0, e1);
                w[sb][1] = pk_bf16(e2, e3);
            }
            swap32(w[0][0], w[1][0]); swap16(w[0][0], w[1][0]);   // -> P(j0), Q(j0)
            swap32(w[0][1], w[1][1]); swap16(w[0][1], w[1][1]);   // -> P(j1), Q(j1)
            swap32(w[2][0], w[3][0]); swap16(w[2][0], w[3][0]);   // -> R(j0), S(j0)
            swap32(w[2][1], w[3][1]); swap16(w[2][1], w[3][1]);   // -> R(j1), S(j1)
            union { u32x4 u; bf16x8 v; } c0, c1;
            c0.u = (u32x4){w[0][0], w[0][1], w[1][0], w[1][1]};
            c1.u = (u32x4){w[2][0], w[2][1], w[3][0], w[3][1]};
            ap0[s] = c0.v;
            ap1[s] = c1.v;
            // row-sum on the MFMA pipe: lane(q,l) receives l[t=q*4+r] in l_acc[s][r]
            l_acc[s] = __builtin_amdgcn_mfma_f32_16x16x32_bf16(ap0[s], vones, l_acc[s], 0, 0, 0);
            l_acc[s] = __builtin_amdgcn_mfma_f32_16x16x32_bf16(ap1[s], vones, l_acc[s], 0, 0, 0);
        }

        // PV: A = P rows (in-register), B = V chunks; each bv frag feeds both row-sets
#pragma unroll
        for (int nb = 0; nb < 4; nb++) {
            const bf16x8 bv0 = *(const bf16x8*)&vb[((size_t)quad * 64 + nb * 16 + l16) * 8];
            const bf16x8 bv1 = *(const bf16x8*)&vb[((size_t)(quad + 4) * 64 + nb * 16 + l16) * 8];
#pragma unroll
            for (int s = 0; s < 2; s++) {
                o_acc[s][nb] = __builtin_amdgcn_mfma_f32_16x16x32_bf16(ap0[s], bv0, o_acc[s][nb], 0, 0, 0);
                o_acc[s][nb] = __builtin_amdgcn_mfma_f32_16x16x32_bf16(ap1[s], bv1, o_acc[s][nb], 0, 0, 0);
            }
        }
        __syncthreads();   // drains t+1 loads; all waves done with buf[p]
    }
#undef STAGE

    // l for local row quad*4+r is already in l_acc[s][r]; correct for pad tokens
    float linv[2][4];
#pragma unroll
    for (int s = 0; s < 2; s++)
#pragma unroll
        for (int r = 0; r < 4; r++)
            linv[s][r] = 1.0f / (l_acc[s][r] - (float)NPAD);

    // epilogue: O[t=s*16+quad*4+r][ch=nb*16+l16] -> stage [t][ch] in dead K/V LDS
    // -> aT packed-B chunks. Per-wave slice 32x72 shorts (9216 total <= 16384).
    unsigned short* ps = smem + wave * (32 * SROW);
#pragma unroll
    for (int s = 0; s < 2; s++)
#pragma unroll
        for (int nb = 0; nb < 4; nb++)
#pragma unroll
            for (int r = 0; r < 4; r++)
                ps[(s * 16 + quad * 4 + r) * SROW + nb * 16 + l16] =
                    f2bf(o_acc[s][nb][r] * linv[s][r]);
    asm volatile("s_waitcnt lgkmcnt(0)" ::: "memory");
    const int k8 = lane >> 3;
#pragma unroll
    for (int it = 0; it < 4; it++) {
        const int tl = (lane & 7) + it * 8;
        const int n = (b << 10) + qt0 + wave * 32 + tl;
        const int ntb = n >> 7, nm = n & 127;
        *(uint4*)&aT[(((size_t)ntb * 8 + h) * 8 + k8) * 1024 + (size_t)nm * 8] =
            *(const uint4*)&ps[tl * SROW + k8 * 8];
    }
}

// ---------------- Launch ----------------
extern "C" void kernel_launch(void* const* d_in, const int* in_sizes, int n_in,
                              void* d_out, int out_size, void* d_ws, size_t ws_size,
                              hipStream_t stream) {
    const float* x     = (const float*)d_in[0];
    const float* cin   = (const float*)d_in[1];
    const float* gamma = (const float*)d_in[2];
    const float* beta  = (const float*)d_in[3];
    const float* w_qkv = (const float*)d_in[4];
    const float* b_qkv = (const float*)d_in[5];
    const float* w_c   = (const float*)d_in[6];
    const float* b_c   = (const float*)d_in[7];
    const float* w_p   = (const float*)d_in[8];
    const float* b_p   = (const float*)d_in[9];
    float* out = (float*)d_out;

    float* ws    = (float*)d_ws;
    float* stats = ws;                                        // 1,024 f
    unsigned short* xnT     = (unsigned short*)(ws + 1024);   // 8,388,608 us
    unsigned short* wqkv_pk = xnT + 8388608;                  // 786,432 us
    unsigned short* wp_pk   = wqkv_pk + 786432;               // 262,144 us
    unsigned short* wc_pk   = wp_pk + 262144;                 // 786,432 us
    unsigned short* cpk     = wc_pk + 786432;                 // 1,572,864 us
    unsigned short* qpk     = cpk + 1572864;                  // 8,388,608 us
    unsigned short* kpk     = qpk + 8388608;                  // 9,437,184 us
    unsigned short* vpk     = kpk + 9437184;                  // 9,437,184 us
    unsigned short* aT      = vpk + 9437184;                  // 8,388,608 us
    // total ~95 MB

    prep_k<<<dim3(1600), 256, 0, stream>>>(x, stats, w_qkv, w_p, w_c, cin,
                                           wqkv_pk, wp_pk, wc_pk, cpk);
    gn_apply_t<<<dim3(16, 8, 16), 256, 0, stream>>>(x, stats, gamma, beta, xnT);
    // qkv + cross MFMA GEMMs fused -> qpk (scaled) / kpk / vpk (+stiles 16,17)
    mgemm_qkvc_k<<<dim3(128, 13), 256, 0, stream>>>(wqkv_pk, xnT, b_qkv,
                                                    wc_pk, cpk, b_c,
                                                    qpk, kpk, vpk);
    // flash attention -> aT (packed B layout for proj)
    flash_k<<<dim3(128, 8), 256, 0, stream>>>(qpk, kpk, vpk, aT);
    // proj MFMA GEMM + bias + residual -> out
    mgemm_proj_k<<<dim3(128, 4), 256, 0, stream>>>(wp_pk, aT, b_p, x, out);
}

// Round 15
// 271.221 us; speedup vs baseline: 1.0461x; 1.0376x over previous
//
#include <hip/hip_runtime.h>

// Problem constants
#define B_   16
#define C_   512
#define T_   1024
#define H_   8
#define D_   64
#define G_   32
#define L_   77
#define S_   1101          // T + L
#define SPAD 1152          // padded S (18 tiles of 64)
#define NPAD 51            // SPAD - S_ : zero-pad tokens each add exp2(0)=1 to l
#define CD_  768
#define BT_  (B_*T_)       // 16384
#define SROW 72            // flash epilogue + mgemm V-epilogue LDS row stride (16B-aligned)
#define QSC  0.18033688011112042f   // 0.125 * log2(e), folded into Q

typedef __bf16 bf16x8 __attribute__((ext_vector_type(8)));
typedef float  f32x4  __attribute__((ext_vector_type(4)));
typedef unsigned int u32x4 __attribute__((ext_vector_type(4)));

static __device__ __forceinline__ unsigned short f2bf(float f) {
    unsigned int u = __float_as_uint(f);
    u = (u + 0x7fffu + ((u >> 16) & 1u)) >> 16;
    return (unsigned short)u;
}

// packed RNE f32x2 -> bf16x2 (single HW instruction)
static __device__ __forceinline__ unsigned int pk_bf16(float a, float b) {
    unsigned int d;
    asm("v_cvt_pk_bf16_f32 %0, %1, %2" : "=v"(d) : "v"(a), "v"(b));
    return d;
}

// R5-R8 lesson (3 failures): EVERY thin path to v_exp_f32 corrupts on this stack
// (raw asm -> NaN; __builtin_amdgcn_exp2f -> absmax 0.156; __expf/native -> 0.135).
// Only the full libm __builtin_exp2f sequence is reliable (0.03125). Do not retry.
static __device__ __forceinline__ float exp2a(float x) {
    return __builtin_exp2f(x);
}

// gfx950 cross-lane swaps (both operands modified):
// swap32: vdst.hi32 <-> vsrc.lo32   => a'={a.lo,b.lo}, b'={a.hi,b.hi}
// swap16: vdst.row1<->vsrc.row0, vdst.row3<->vsrc.row2 (rows = 16 lanes)
static __device__ __forceinline__ void swap32(unsigned& a, unsigned& b) {
    asm volatile("v_permlane32_swap_b32 %0, %1" : "+v"(a), "+v"(b));
}
static __device__ __forceinline__ void swap16(unsigned& a, unsigned& b) {
    asm volatile("v_permlane16_swap_b32 %0, %1" : "+v"(a), "+v"(b));
}

static __device__ __forceinline__ void gload_lds16(const unsigned short* g,
                                                   unsigned short* l) {
    __builtin_amdgcn_global_load_lds(
        (const __attribute__((address_space(1))) unsigned int*)g,
        (__attribute__((address_space(3))) unsigned int*)l, 16, 0, 0);
}

// -------- prep: GN stats (0..511) + weight packing (512..1407) + c pack (1408..1599)
__global__ __launch_bounds__(256) void prep_k(const float* __restrict__ x,
                                              float* __restrict__ stats,
                                              const float* __restrict__ w_qkv,
                                              const float* __restrict__ w_p,
                                              const float* __restrict__ w_c,
                                              const float* __restrict__ cin,
                                              unsigned short* __restrict__ wqkv_pk,
                                              unsigned short* __restrict__ wp_pk,
                                              unsigned short* __restrict__ wc_pk,
                                              unsigned short* __restrict__ cpk) {
    const int tid = threadIdx.x;
    if (blockIdx.x < 512) {
        const int bg = blockIdx.x;
        const float* p = x + (size_t)bg * 16384;
        float s = 0.f, s2 = 0.f;
        for (int i = tid; i < 16384; i += 256) {
            float v = p[i];
            s += v; s2 += v * v;
        }
        __shared__ float rs[256], rs2[256];
        rs[tid] = s; rs2[tid] = s2;
        __syncthreads();
        for (int off = 128; off > 0; off >>= 1) {
            if (tid < off) { rs[tid] += rs[tid + off]; rs2[tid] += rs2[tid + off]; }
            __syncthreads();
        }
        if (tid == 0) {
            float mean = rs[0] * (1.0f / 16384.0f);
            float var  = rs2[0] * (1.0f / 16384.0f) - mean * mean;
            stats[2 * bg]     = mean;
            stats[2 * bg + 1] = rsqrtf(var + 1e-5f);
        }
        return;
    }
    if (blockIdx.x < 1408) {
        const int cid = (blockIdx.x - 512) * 256 + tid;   // 229376 chunks
        const float* src;
        unsigned short* dst;
        if (cid < 98304) {                 // w_qkv 1536x512, KT=8
            const int ml = cid & 127, k8 = (cid >> 7) & 7, kt = (cid >> 10) & 7, mt = cid >> 13;
            src = w_qkv + (size_t)(mt * 128 + ml) * 512 + kt * 64 + k8 * 8;
            dst = wqkv_pk + (size_t)cid * 8;
        } else if (cid < 131072) {         // w_p 512x512, KT=8
            const int c2 = cid - 98304;
            const int ml = c2 & 127, k8 = (c2 >> 7) & 7, kt = (c2 >> 10) & 7, mt = c2 >> 13;
            src = w_p + (size_t)(mt * 128 + ml) * 512 + kt * 64 + k8 * 8;
            dst = wp_pk + (size_t)c2 * 8;
        } else {                           // w_c 1024x768, KT=12
            const int c3 = cid - 131072;
            const int ml = c3 & 127, k8 = (c3 >> 7) & 7;
            const int ktmt = c3 >> 10;
            const int kt = ktmt % 12, mt = ktmt / 12;
            src = w_c + (size_t)(mt * 128 + ml) * 768 + kt * 64 + k8 * 8;
            dst = wc_pk + (size_t)c3 * 8;
        }
        const float4 v0 = *(const float4*)src, v1 = *(const float4*)(src + 4);
        unsigned short tmp[8];
        tmp[0] = f2bf(v0.x); tmp[1] = f2bf(v0.y); tmp[2] = f2bf(v0.z); tmp[3] = f2bf(v0.w);
        tmp[4] = f2bf(v1.x); tmp[5] = f2bf(v1.y); tmp[6] = f2bf(v1.z); tmp[7] = f2bf(v1.w);
        *(uint4*)dst = *(uint4*)tmp;
        return;
    }
    // pack cross input c [b][768][77] -> B layout per batch (KT=12, N padded to 128)
    const int idx2 = blockIdx.x - 1408;     // 192 = 12 kt * 16 b
    const int kt = idx2 % 12, b = idx2 / 12;
#pragma unroll
    for (int it = 0; it < 4; it++) {
        const int idx = it * 256 + tid;     // 1024 chunks per (kt,b)
        const int k8 = idx >> 7, l = idx & 127;
        unsigned short tmp[8];
        const float* src = cin + ((size_t)b * CD_ + kt * 64 + k8 * 8) * L_ + l;
#pragma unroll
        for (int q = 0; q < 8; q++)
            tmp[q] = (l < L_) ? f2bf(src[(size_t)q * L_]) : (unsigned short)0;
        *(uint4*)&cpk[(size_t)b * 98304 + ((size_t)(kt * 8 + k8)) * 1024 + (size_t)l * 8] =
            *(uint4*)tmp;
    }
}

// -------- GroupNorm apply + transpose + bf16 pack into GEMM-B layout --------
__global__ __launch_bounds__(256) void gn_apply_t(const float* __restrict__ x,
                                                  const float* __restrict__ stats,
                                                  const float* __restrict__ gamma,
                                                  const float* __restrict__ beta,
                                                  unsigned short* __restrict__ xnT) {
    const int t0 = blockIdx.x * 64, kt = blockIdx.y, b = blockIdx.z;
    const int c0 = kt * 64;
    const int tid = threadIdx.x;
    __shared__ float st[64][66];   // [t][c]
#pragma unroll
    for (int it = 0; it < 4; it++) {
        const int fid = it * 256 + tid;
        const int ci = fid >> 4, t4 = (fid & 15) * 4;
        const int c = c0 + ci;
        const float4 xv = *(const float4*)&x[((size_t)(b * C_ + c) << 10) + t0 + t4];
        const int bg = b * G_ + (c >> 4);
        const float mean = stats[2 * bg], istd = stats[2 * bg + 1];
        const float gs = gamma[c] * istd, gb = beta[c] - mean * gs;
        st[t4 + 0][ci] = xv.x * gs + gb;
        st[t4 + 1][ci] = xv.y * gs + gb;
        st[t4 + 2][ci] = xv.z * gs + gb;
        st[t4 + 3][ci] = xv.w * gs + gb;
    }
    __syncthreads();
#pragma unroll
    for (int it = 0; it < 2; it++) {
        const int cid = it * 256 + tid;
        const int k8 = cid >> 6, tl = cid & 63;
        const int n = (b << 10) + t0 + tl;
        const int nt = n >> 7, nm = n & 127;
        unsigned short tmp[8];
        const float* src = &st[tl][k8 * 8];
#pragma unroll
        for (int q = 0; q < 8; q++) tmp[q] = f2bf(src[q]);
        *(uint4*)&xnT[(((size_t)nt * 8 + kt) * 8 + k8) * 1024 + (size_t)nm * 8] = *(uint4*)tmp;
    }
}

// ---------------- MFMA bf16 GEMM body, 128x128 tile, BK=64 (R4/R9-proven 2-barrier) -------
// MODE 0: qkv (KT=8)  -> packed-chunk Q(scaled)/K/V (+bias).
// MODE 1: proj (KT=8) -> fp32 out = C + bias + resid.
// MODE 2: cross (KT=12, batched zz) -> Kc/Vc chunks at stiles 16/17, pad->0.
template<int MODE, int KT>
static __device__ __forceinline__ void mgemm_body(const unsigned short* __restrict__ Apk,
                                                  const unsigned short* __restrict__ Bpk,
                                                  const float* __restrict__ bias,
                                                  const float* __restrict__ resid,
                                                  unsigned short* __restrict__ qpk,
                                                  unsigned short* __restrict__ kpk,
                                                  unsigned short* __restrict__ vpk,
                                                  float* __restrict__ outp,
                                                  unsigned short* lds,
                                                  const int nt, const int mt, const int zz) {
    const int tid = threadIdx.x, wave = tid >> 6, lane = tid & 63;
    const int quad = lane >> 4, l16 = lane & 15;
    const int mw = (wave & 1) * 64, nw = (wave >> 1) * 64;

    f32x4 acc[4][4];
#pragma unroll
    for (int i = 0; i < 4; i++)
#pragma unroll
        for (int j = 0; j < 4; j++) acc[i][j] = (f32x4){0.f, 0.f, 0.f, 0.f};

    const unsigned short* Ab = Apk + (size_t)mt * KT * 8192;
    const unsigned short* Bb = Bpk + ((MODE == 2) ? (size_t)zz * KT * 8192 : 0)
                                   + (size_t)nt * KT * 8192;

    for (int kt = 0; kt < KT; kt++) {
        const unsigned short* as = Ab + kt * 8192 + wave * 2048 + lane * 8;
        const unsigned short* bs = Bb + kt * 8192 + wave * 2048 + lane * 8;
        unsigned short* la = lds + wave * 2048;
        unsigned short* lb = lds + 8192 + wave * 2048;
#pragma unroll
        for (int j = 0; j < 4; j++) {
            gload_lds16(as + j * 512, la + j * 512);
            gload_lds16(bs + j * 512, lb + j * 512);
        }
        __syncthreads();
#pragma unroll
        for (int kh = 0; kh < 2; kh++) {
            const int k8 = kh * 4 + quad;
            bf16x8 af[4], bfr[4];
#pragma unroll
            for (int i = 0; i < 4; i++) {
                af[i]  = *(const bf16x8*)&lds[(size_t)(k8 * 128 + mw + i * 16 + l16) * 8];
                bfr[i] = *(const bf16x8*)&lds[8192 + (size_t)(k8 * 128 + nw + i * 16 + l16) * 8];
            }
#pragma unroll
            for (int mi = 0; mi < 4; mi++)
#pragma unroll
                for (int ni = 0; ni < 4; ni++)
                    acc[mi][ni] = __builtin_amdgcn_mfma_f32_16x16x32_bf16(
                        af[mi], bfr[ni], acc[mi][ni], 0, 0, 0);
        }
        __syncthreads();
    }

    const int gm0 = mt * 128 + mw;
    const int gn0 = nt * 128 + nw;

    if (MODE == 1) {
        const int b = gn0 >> 10, t0 = gn0 & 1023;
#pragma unroll
        for (int mi = 0; mi < 4; mi++) {
#pragma unroll
            for (int r = 0; r < 4; r++) {
                const int m = gm0 + mi * 16 + quad * 4 + r;
                const float bv = bias[m];
                const size_t rowb = ((size_t)(b * C_ + m) << 10) + t0;
#pragma unroll
                for (int ni = 0; ni < 4; ni++) {
                    const size_t a = rowb + ni * 16 + l16;
                    outp[a] = acc[mi][ni][r] + bv + resid[a];
                }
            }
        }
        return;
    }

    // regions are block-uniform (128-tile never straddles a 512 boundary)
    const int region = gm0 >> 9;              // MODE0: 0=Q 1=K 2=V ; MODE2: 0=Kc 1=Vc
    const int h = (gm0 & 511) >> 6;
    const int b = (MODE == 2) ? zz : (gn0 >> 10);
    const int bh = b * 8 + h;
    const bool vregion = (MODE == 0) ? (region == 2) : (region == 1);

    if (!vregion) {
        // LDS-free packed-chunk writes for Q / K / Kc
        const float sc = (MODE == 0 && region == 0) ? QSC : 1.0f;
        unsigned short* base;
        int trow0;                            // token row base within stile, t64 base
        if (MODE == 0) {
            base = (region == 0) ? qpk + (size_t)bh * 16 * 4096
                                 : kpk + (size_t)bh * 18 * 4096;
            trow0 = gn0 & 1023;
        } else {
            base = kpk + (size_t)(bh * 18 + 16 + (gn0 >> 6)) * 4096;
            trow0 = -1;
        }
#pragma unroll
        for (int mi = 0; mi < 4; mi++) {
            const int k8 = mi * 2 + (quad >> 1);
            const int sub = (quad & 1) * 4;
#pragma unroll
            for (int ni = 0; ni < 4; ni++) {
                float vv[4];
                bool valid = true;
                if (MODE == 2) valid = (gn0 + ni * 16 + l16) < L_;
#pragma unroll
                for (int r = 0; r < 4; r++)
                    vv[r] = valid ? (acc[mi][ni][r] + bias[gm0 + mi * 16 + quad * 4 + r]) * sc
                                  : 0.f;
                uint2 d;
                d.x = pk_bf16(vv[0], vv[1]);
                d.y = pk_bf16(vv[2], vv[3]);
                unsigned short* dst;
                if (MODE == 0) {
                    const int t = trow0 + ni * 16 + l16;
                    dst = base + (size_t)(t >> 6) * 4096 + ((size_t)k8 * 64 + (t & 63)) * 8 + sub;
                } else {
                    const int row = ni * 16 + l16;
                    dst = base + ((size_t)k8 * 64 + row) * 8 + sub;
                }
                *(uint2*)dst = d;
            }
        }
    } else {
        // V: LDS transpose then chunk stores (chunks are 8 s-values per ch)
        unsigned short* wlds = lds + wave * 4608;   // 64 ch x 72
#pragma unroll
        for (int mi = 0; mi < 4; mi++)
#pragma unroll
            for (int ni = 0; ni < 4; ni++) {
                bool valid = true;
                if (MODE == 2) valid = (gn0 + ni * 16 + l16) < L_;
#pragma unroll
                for (int r = 0; r < 4; r++) {
                    const float v = valid ? acc[mi][ni][r] + bias[gm0 + mi * 16 + quad * 4 + r]
                                          : 0.f;
                    wlds[(mi * 16 + quad * 4 + r) * SROW + ni * 16 + l16] = f2bf(v);
                }
            }
        __syncthreads();
        const int stile = (MODE == 0) ? ((gn0 & 1023) >> 6) : (16 + (gn0 >> 6));
        unsigned short* dst = vpk + (size_t)(bh * 18 + stile) * 4096;
        const int sk8 = lane & 7, cb = lane >> 3;
#pragma unroll
        for (int it = 0; it < 8; it++) {
            const int ch = it * 8 + cb;
            *(uint4*)&dst[((size_t)sk8 * 64 + ch) * 8] =
                *(const uint4*)&wlds[ch * SROW + sk8 * 8];
        }
    }
}

// qkv (y=0..11) + cross (y=12, 128 blocks = 8 mt x 16 batch) fused in one dispatch:
// cross alone ran at 0.5 blocks/CU (~pure serial region); now hidden under qkv.
__global__ __launch_bounds__(256) void mgemm_qkvc_k(const unsigned short* __restrict__ wqkv_pk,
                                                    const unsigned short* __restrict__ xnT,
                                                    const float* __restrict__ b_qkv,
                                                    const unsigned short* __restrict__ wc_pk,
                                                    const unsigned short* __restrict__ cpk,
                                                    const float* __restrict__ b_c,
                                                    unsigned short* __restrict__ qpk,
                                                    unsigned short* __restrict__ kpk,
                                                    unsigned short* __restrict__ vpk) {
    __shared__ unsigned short lds[18432];   // staging A[0,8192) B[8192,16384); V-epi 4x4608
    if (blockIdx.y < 12) {
        mgemm_body<0, 8>(wqkv_pk, xnT, b_qkv, nullptr, qpk, kpk, vpk, nullptr,
                         lds, blockIdx.x, blockIdx.y, 0);
    } else {
        mgemm_body<2, 12>(wc_pk, cpk, b_c, nullptr, nullptr, kpk, vpk, nullptr,
                          lds, 0, blockIdx.x & 7, blockIdx.x >> 3);
    }
}

__global__ __launch_bounds__(256) void mgemm_proj_k(const unsigned short* __restrict__ Apk,
                                                    const unsigned short* __restrict__ Bpk,
                                                    const float* __restrict__ bias,
                                                    const float* __restrict__ resid,
                                                    float* __restrict__ outp) {
    __shared__ unsigned short lds[18432];
    mgemm_body<1, 8>(Apk, Bpk, bias, resid, nullptr, nullptr, nullptr, outp,
                     lds, blockIdx.x, blockIdx.y, 0);
}

// ---------------- Flash attention (swapped QK^T, exp2, P in-register, MFMA row-sum) -------
// Grid (bh=128, qt=8). Block: 128 q-tokens, 4 waves x 32 rows (2 B-frag sets).
// R14 lesson: the single-barrier K/V dbuf intermittently corrupted output under
// repeated graph replay (post-timing tripwire absmax 3.9 after 7 clean benches) —
// an m152-class async-DMA/barrier race. TWO barriers per stile now: barrier ->
// STAGE(t+1) issued -> compute tile t -> barrier. Stage still issued BEFORE compute,
// so HBM latency remains covered by QK+softmax+PV; the extra barrier restores the
// conservative ordering (buf p^1 overwrite strictly after a barrier all waves passed
// post-read, and compute strictly between drains).
__global__ __launch_bounds__(256, 4) void flash_k(const unsigned short* __restrict__ qpk,
                                                  const unsigned short* __restrict__ kpk,
                                                  const unsigned short* __restrict__ vpk,
                                                  unsigned short* __restrict__ aT) {
    __shared__ __align__(16) unsigned short smem[16384];  // K dbuf [0,8192) V dbuf [8192,16384)

    const int tid  = threadIdx.x;
    const int wave = tid >> 6, lane = tid & 63;
    const int quad = lane >> 4, l16 = lane & 15;
    const int bh  = blockIdx.x;
    const int b = bh >> 3, h = bh & 7;
    const int qt0 = blockIdx.y * 128;

    // Q B-frags for two 16-row sets; wave's tokens = qt0 + wave*32 + set*16 + l16
    const unsigned short* qtb = qpk + ((size_t)bh * 16 + blockIdx.y * 2 + (wave >> 1)) * 4096;
    const int qr0 = (wave & 1) * 32 + l16;
    bf16x8 bq0[2], bq1[2];
#pragma unroll
    for (int s = 0; s < 2; s++) {
        bq0[s] = *(const bf16x8*)&qtb[((size_t)quad * 64 + qr0 + s * 16) * 8];
        bq1[s] = *(const bf16x8*)&qtb[((size_t)(quad + 4) * 64 + qr0 + s * 16) * 8];
    }

    // all-ones bf16 B-fragment for the row-sum MFMA
    union { u32x4 u; bf16x8 v; } one_u;
    one_u.u = (u32x4){0x3F803F80u, 0x3F803F80u, 0x3F803F80u, 0x3F803F80u};
    const bf16x8 vones = one_u.v;

    const unsigned short* kbase = kpk + (size_t)bh * 18 * 4096 + wave * 1024 + lane * 8;
    const unsigned short* vbase = vpk + (size_t)bh * 18 * 4096 + wave * 1024 + lane * 8;

#define STAGE(p, t) do {                                                  \
        const unsigned short* kg = kbase + (size_t)(t) * 4096;            \
        const unsigned short* vg = vbase + (size_t)(t) * 4096;            \
        unsigned short* lkp = smem + (p) * 4096 + wave * 1024;            \
        unsigned short* lvp = smem + 8192 + (p) * 4096 + wave * 1024;     \
        gload_lds16(kg, lkp);       gload_lds16(kg + 512, lkp + 512);     \
        gload_lds16(vg, lvp);       gload_lds16(vg + 512, lvp + 512);     \
    } while (0)

    f32x4 l_acc[2];
    f32x4 o_acc[2][4];
#pragma unroll
    for (int s = 0; s < 2; s++) {
        l_acc[s] = (f32x4){0.f, 0.f, 0.f, 0.f};
#pragma unroll
        for (int nb = 0; nb < 4; nb++) o_acc[s][nb] = (f32x4){0.f, 0.f, 0.f, 0.f};
    }

    STAGE(0, 0);
    __syncthreads();

    for (int t = 0; t < 18; t++) {
        const int p = t & 1;
        if (t < 17) STAGE(p ^ 1, t + 1);   // issued BEFORE compute: latency covered
        const unsigned short* kb = smem + p * 4096;
        const unsigned short* vb = smem + 8192 + p * 4096;

        // QK^T: A = K rows (sb*16+l16), B = Q -> sacc[s][sb] = S[t=l16][s=sb*16+quad*4+r]
        f32x4 sacc[2][4];
#pragma unroll
        for (int sb = 0; sb < 4; sb++) {
            const bf16x8 ak0 = *(const bf16x8*)&kb[((size_t)quad * 64 + sb * 16 + l16) * 8];
            const bf16x8 ak1 = *(const bf16x8*)&kb[((size_t)(quad + 4) * 64 + sb * 16 + l16) * 8];
#pragma unroll
            for (int s = 0; s < 2; s++) {
                f32x4 z = (f32x4){0.f, 0.f, 0.f, 0.f};
                z = __builtin_amdgcn_mfma_f32_16x16x32_bf16(ak0, bq0[s], z, 0, 0, 0);
                z = __builtin_amdgcn_mfma_f32_16x16x32_bf16(ak1, bq1[s], z, 0, 0, 0);
                sacc[s][sb] = z;
            }
        }

        // softmax numerator + in-register transpose to PV-A layout.
        bf16x8 ap0[2], ap1[2];
#pragma unroll
        for (int s = 0; s < 2; s++) {
            unsigned w[4][2];
#pragma unroll
            for (int sb = 0; sb < 4; sb++) {
                const float e0 = exp2a(sacc[s][sb][0]);
                const float e1 = exp2a(sacc[s][sb][1]);
                const float e2 = exp2a(sacc[s][sb][2]);
                const float e3 = exp2a(sacc[s][sb][3]);
                w[sb][0] = pk_bf16(e0, e1);
                w[sb][1] = pk_bf16(e2, e3);
            }
            swap32(w[0][0], w[1][0]); swap16(w[0][0], w[1][0]);   // -> P(j0), Q(j0)
            swap32(w[0][1], w[1][1]); swap16(w[0][1], w[1][1]);   // -> P(j1), Q(j1)
            swap32(w[2][0], w[3][0]); swap16(w[2][0], w[3][0]);   // -> R(j0), S(j0)
            swap32(w[2][1], w[3][1]); swap16(w[2][1], w[3][1]);   // -> R(j1), S(j1)
            union { u32x4 u; bf16x8 v; } c0, c1;
            c0.u = (u32x4){w[0][0], w[0][1], w[1][0], w[1][1]};
            c1.u = (u32x4){w[2][0], w[2][1], w[3][0], w[3][1]};
            ap0[s] = c0.v;
            ap1[s] = c1.v;
            // row-sum on the MFMA pipe: lane(q,l) receives l[t=q*4+r] in l_acc[s][r]
            l_acc[s] = __builtin_amdgcn_mfma_f32_16x16x32_bf16(ap0[s], vones, l_acc[s], 0, 0, 0);
            l_acc[s] = __builtin_amdgcn_mfma_f32_16x16x32_bf16(ap1[s], vones, l_acc[s], 0, 0, 0);
        }

        // PV: A = P rows (in-register), B = V chunks; each bv frag feeds both row-sets
#pragma unroll
        for (int nb = 0; nb < 4; nb++) {
            const bf16x8 bv0 = *(const bf16x8*)&vb[((size_t)quad * 64 + nb * 16 + l16) * 8];
            const bf16x8 bv1 = *(const bf16x8*)&vb[((size_t)(quad + 4) * 64 + nb * 16 + l16) * 8];
#pragma unroll
            for (int s = 0; s < 2; s++) {
                o_acc[s][nb] = __builtin_amdgcn_mfma_f32_16x16x32_bf16(ap0[s], bv0, o_acc[s][nb], 0, 0, 0);
                o_acc[s][nb] = __builtin_amdgcn_mfma_f32_16x16x32_bf16(ap1[s], bv1, o_acc[s][nb], 0, 0, 0);
            }
        }
        __syncthreads();   // drain t+1 loads (covered by the compute above)
        __syncthreads();   // conservative ordering: no wave may touch buf p^1 until
                           // every wave has passed the post-compute drain (R14 race fix)
    }
#undef STAGE

    // l for local row quad*4+r is already in l_acc[s][r]; correct for pad tokens
    float linv[2][4];
#pragma unroll
    for (int s = 0; s < 2; s++)
#pragma unroll
        for (int r = 0; r < 4; r++)
            linv[s][r] = 1.0f / (l_acc[s][r] - (float)NPAD);

    // epilogue: O[t=s*16+quad*4+r][ch=nb*16+l16] -> stage [t][ch] in dead K/V LDS
    // -> aT packed-B chunks. Per-wave slice 32x72 shorts (9216 total <= 16384).
    unsigned short* ps = smem + wave * (32 * SROW);
#pragma unroll
    for (int s = 0; s < 2; s++)
#pragma unroll
        for (int nb = 0; nb < 4; nb++)
#pragma unroll
            for (int r = 0; r < 4; r++)
                ps[(s * 16 + quad * 4 + r) * SROW + nb * 16 + l16] =
                    f2bf(o_acc[s][nb][r] * linv[s][r]);
    asm volatile("s_waitcnt lgkmcnt(0)" ::: "memory");
    const int k8 = lane >> 3;
#pragma unroll
    for (int it = 0; it < 4; it++) {
        const int tl = (lane & 7) + it * 8;
        const int n = (b << 10) + qt0 + wave * 32 + tl;
        const int ntb = n >> 7, nm = n & 127;
        *(uint4*)&aT[(((size_t)ntb * 8 + h) * 8 + k8) * 1024 + (size_t)nm * 8] =
            *(const uint4*)&ps[tl * SROW + k8 * 8];
    }
}

// ---------------- Launch ----------------
extern "C" void kernel_launch(void* const* d_in, const int* in_sizes, int n_in,
                              void* d_out, int out_size, void* d_ws, size_t ws_size,
                              hipStream_t stream) {
    const float* x     = (const float*)d_in[0];
    const float* cin   = (const float*)d_in[1];
    const float* gamma = (const float*)d_in[2];
    const float* beta  = (const float*)d_in[3];
    const float* w_qkv = (const float*)d_in[4];
    const float* b_qkv = (const float*)d_in[5];
    const float* w_c   = (const float*)d_in[6];
    const float* b_c   = (const float*)d_in[7];
    const float* w_p   = (const float*)d_in[8];
    const float* b_p   = (const float*)d_in[9];
    float* out = (float*)d_out;

    float* ws    = (float*)d_ws;
    float* stats = ws;                                        // 1,024 f
    unsigned short* xnT     = (unsigned short*)(ws + 1024);   // 8,388,608 us
    unsigned short* wqkv_pk = xnT + 8388608;                  // 786,432 us
    unsigned short* wp_pk   = wqkv_pk + 786432;               // 262,144 us
    unsigned short* wc_pk   = wp_pk + 262144;                 // 786,432 us
    unsigned short* cpk     = wc_pk + 786432;                 // 1,572,864 us
    unsigned short* qpk     = cpk + 1572864;                  // 8,388,608 us
    unsigned short* kpk     = qpk + 8388608;                  // 9,437,184 us
    unsigned short* vpk     = kpk + 9437184;                  // 9,437,184 us
    unsigned short* aT      = vpk + 9437184;                  // 8,388,608 us
    // total ~95 MB

    prep_k<<<dim3(1600), 256, 0, stream>>>(x, stats, w_qkv, w_p, w_c, cin,
                                           wqkv_pk, wp_pk, wc_pk, cpk);
    gn_apply_t<<<dim3(16, 8, 16), 256, 0, stream>>>(x, stats, gamma, beta, xnT);
    // qkv + cross MFMA GEMMs fused -> qpk (scaled) / kpk / vpk (+stiles 16,17)
    mgemm_qkvc_k<<<dim3(128, 13), 256, 0, stream>>>(wqkv_pk, xnT, b_qkv,
                                                    wc_pk, cpk, b_c,
                                                    qpk, kpk, vpk);
    // flash attention -> aT (packed B layout for proj)
    flash_k<<<dim3(128, 8), 256, 0, stream>>>(qpk, kpk, vpk, aT);
    // proj MFMA GEMM + bias + residual -> out
    mgemm_proj_k<<<dim3(128, 4), 256, 0, stream>>>(wp_pk, aT, b_p, x, out);
}

// Round 16
// 262.576 us; speedup vs baseline: 1.0805x; 1.0329x over previous
//
#include <hip/hip_runtime.h>

// Problem constants
#define B_   16
#define C_   512
#define T_   1024
#define H_   8
#define D_   64
#define G_   32
#define L_   77
#define S_   1101          // T + L
#define SPAD 1152          // padded S (18 tiles of 64)
#define NPAD 51            // SPAD - S_ : zero-pad tokens each add exp2(0)=1 to l
#define CD_  768
#define BT_  (B_*T_)       // 16384
#define SROW 72            // flash epilogue + mgemm V-epilogue LDS row stride (16B-aligned)
#define QSC  0.18033688011112042f   // 0.125 * log2(e), folded into Q

typedef __bf16 bf16x8 __attribute__((ext_vector_type(8)));
typedef float  f32x4  __attribute__((ext_vector_type(4)));
typedef unsigned int u32x4 __attribute__((ext_vector_type(4)));

static __device__ __forceinline__ unsigned short f2bf(float f) {
    unsigned int u = __float_as_uint(f);
    u = (u + 0x7fffu + ((u >> 16) & 1u)) >> 16;
    return (unsigned short)u;
}

// packed RNE f32x2 -> bf16x2 (single HW instruction)
static __device__ __forceinline__ unsigned int pk_bf16(float a, float b) {
    unsigned int d;
    asm("v_cvt_pk_bf16_f32 %0, %1, %2" : "=v"(d) : "v"(a), "v"(b));
    return d;
}

// R5-R8 lesson (3 failures): EVERY thin path to v_exp_f32 corrupts on this stack
// (raw asm -> NaN; __builtin_amdgcn_exp2f -> absmax 0.156; __expf/native -> 0.135).
// Only the full libm __builtin_exp2f sequence is reliable (0.03125). Do not retry.
static __device__ __forceinline__ float exp2a(float x) {
    return __builtin_exp2f(x);
}

// gfx950 cross-lane swaps (both operands modified):
// swap32: vdst.hi32 <-> vsrc.lo32   => a'={a.lo,b.lo}, b'={a.hi,b.hi}
// swap16: vdst.row1<->vsrc.row0, vdst.row3<->vsrc.row2 (rows = 16 lanes)
static __device__ __forceinline__ void swap32(unsigned& a, unsigned& b) {
    asm volatile("v_permlane32_swap_b32 %0, %1" : "+v"(a), "+v"(b));
}
static __device__ __forceinline__ void swap16(unsigned& a, unsigned& b) {
    asm volatile("v_permlane16_swap_b32 %0, %1" : "+v"(a), "+v"(b));
}

static __device__ __forceinline__ void gload_lds16(const unsigned short* g,
                                                   unsigned short* l) {
    __builtin_amdgcn_global_load_lds(
        (const __attribute__((address_space(1))) unsigned int*)g,
        (__attribute__((address_space(3))) unsigned int*)l, 16, 0, 0);
}

// -------- prep: GN stats (0..511) + weight packing (512..1407) + c pack (1408..1599)
__global__ __launch_bounds__(256) void prep_k(const float* __restrict__ x,
                                              float* __restrict__ stats,
                                              const float* __restrict__ w_qkv,
                                              const float* __restrict__ w_p,
                                              const float* __restrict__ w_c,
                                              const float* __restrict__ cin,
                                              unsigned short* __restrict__ wqkv_pk,
                                              unsigned short* __restrict__ wp_pk,
                                              unsigned short* __restrict__ wc_pk,
                                              unsigned short* __restrict__ cpk) {
    const int tid = threadIdx.x;
    if (blockIdx.x < 512) {
        const int bg = blockIdx.x;
        const float* p = x + (size_t)bg * 16384;
        float s = 0.f, s2 = 0.f;
        for (int i = tid; i < 16384; i += 256) {
            float v = p[i];
            s += v; s2 += v * v;
        }
        __shared__ float rs[256], rs2[256];
        rs[tid] = s; rs2[tid] = s2;
        __syncthreads();
        for (int off = 128; off > 0; off >>= 1) {
            if (tid < off) { rs[tid] += rs[tid + off]; rs2[tid] += rs2[tid + off]; }
            __syncthreads();
        }
        if (tid == 0) {
            float mean = rs[0] * (1.0f / 16384.0f);
            float var  = rs2[0] * (1.0f / 16384.0f) - mean * mean;
            stats[2 * bg]     = mean;
            stats[2 * bg + 1] = rsqrtf(var + 1e-5f);
        }
        return;
    }
    if (blockIdx.x < 1408) {
        const int cid = (blockIdx.x - 512) * 256 + tid;   // 229376 chunks
        const float* src;
        unsigned short* dst;
        if (cid < 98304) {                 // w_qkv 1536x512, KT=8
            const int ml = cid & 127, k8 = (cid >> 7) & 7, kt = (cid >> 10) & 7, mt = cid >> 13;
            src = w_qkv + (size_t)(mt * 128 + ml) * 512 + kt * 64 + k8 * 8;
            dst = wqkv_pk + (size_t)cid * 8;
        } else if (cid < 131072) {         // w_p 512x512, KT=8
            const int c2 = cid - 98304;
            const int ml = c2 & 127, k8 = (c2 >> 7) & 7, kt = (c2 >> 10) & 7, mt = c2 >> 13;
            src = w_p + (size_t)(mt * 128 + ml) * 512 + kt * 64 + k8 * 8;
            dst = wp_pk + (size_t)c2 * 8;
        } else {                           // w_c 1024x768, KT=12
            const int c3 = cid - 131072;
            const int ml = c3 & 127, k8 = (c3 >> 7) & 7;
            const int ktmt = c3 >> 10;
            const int kt = ktmt % 12, mt = ktmt / 12;
            src = w_c + (size_t)(mt * 128 + ml) * 768 + kt * 64 + k8 * 8;
            dst = wc_pk + (size_t)c3 * 8;
        }
        const float4 v0 = *(const float4*)src, v1 = *(const float4*)(src + 4);
        unsigned short tmp[8];
        tmp[0] = f2bf(v0.x); tmp[1] = f2bf(v0.y); tmp[2] = f2bf(v0.z); tmp[3] = f2bf(v0.w);
        tmp[4] = f2bf(v1.x); tmp[5] = f2bf(v1.y); tmp[6] = f2bf(v1.z); tmp[7] = f2bf(v1.w);
        *(uint4*)dst = *(uint4*)tmp;
        return;
    }
    // pack cross input c [b][768][77] -> B layout per batch (KT=12, N padded to 128)
    const int idx2 = blockIdx.x - 1408;     // 192 = 12 kt * 16 b
    const int kt = idx2 % 12, b = idx2 / 12;
#pragma unroll
    for (int it = 0; it < 4; it++) {
        const int idx = it * 256 + tid;     // 1024 chunks per (kt,b)
        const int k8 = idx >> 7, l = idx & 127;
        unsigned short tmp[8];
        const float* src = cin + ((size_t)b * CD_ + kt * 64 + k8 * 8) * L_ + l;
#pragma unroll
        for (int q = 0; q < 8; q++)
            tmp[q] = (l < L_) ? f2bf(src[(size_t)q * L_]) : (unsigned short)0;
        *(uint4*)&cpk[(size_t)b * 98304 + ((size_t)(kt * 8 + k8)) * 1024 + (size_t)l * 8] =
            *(uint4*)tmp;
    }
}

// -------- GroupNorm apply + transpose + bf16 pack into GEMM-B layout --------
__global__ __launch_bounds__(256) void gn_apply_t(const float* __restrict__ x,
                                                  const float* __restrict__ stats,
                                                  const float* __restrict__ gamma,
                                                  const float* __restrict__ beta,
                                                  unsigned short* __restrict__ xnT) {
    const int t0 = blockIdx.x * 64, kt = blockIdx.y, b = blockIdx.z;
    const int c0 = kt * 64;
    const int tid = threadIdx.x;
    __shared__ float st[64][66];   // [t][c]
#pragma unroll
    for (int it = 0; it < 4; it++) {
        const int fid = it * 256 + tid;
        const int ci = fid >> 4, t4 = (fid & 15) * 4;
        const int c = c0 + ci;
        const float4 xv = *(const float4*)&x[((size_t)(b * C_ + c) << 10) + t0 + t4];
        const int bg = b * G_ + (c >> 4);
        const float mean = stats[2 * bg], istd = stats[2 * bg + 1];
        const float gs = gamma[c] * istd, gb = beta[c] - mean * gs;
        st[t4 + 0][ci] = xv.x * gs + gb;
        st[t4 + 1][ci] = xv.y * gs + gb;
        st[t4 + 2][ci] = xv.z * gs + gb;
        st[t4 + 3][ci] = xv.w * gs + gb;
    }
    __syncthreads();
#pragma unroll
    for (int it = 0; it < 2; it++) {
        const int cid = it * 256 + tid;
        const int k8 = cid >> 6, tl = cid & 63;
        const int n = (b << 10) + t0 + tl;
        const int nt = n >> 7, nm = n & 127;
        unsigned short tmp[8];
        const float* src = &st[tl][k8 * 8];
#pragma unroll
        for (int q = 0; q < 8; q++) tmp[q] = f2bf(src[q]);
        *(uint4*)&xnT[(((size_t)nt * 8 + kt) * 8 + k8) * 1024 + (size_t)nm * 8] = *(uint4*)tmp;
    }
}

// ---------------- MFMA bf16 GEMM body, 128x128 tile, BK=64 (R4/R9-proven 2-barrier) -------
// MODE 0: qkv (KT=8)  -> packed-chunk Q(scaled)/K/V (+bias).
// MODE 1: proj (KT=8) -> fp32 out = C + bias + resid.
// MODE 2: cross (KT=12, batched zz) -> Kc/Vc chunks at stiles 16/17, pad->0.
template<int MODE, int KT>
static __device__ __forceinline__ void mgemm_body(const unsigned short* __restrict__ Apk,
                                                  const unsigned short* __restrict__ Bpk,
                                                  const float* __restrict__ bias,
                                                  const float* __restrict__ resid,
                                                  unsigned short* __restrict__ qpk,
                                                  unsigned short* __restrict__ kpk,
                                                  unsigned short* __restrict__ vpk,
                                                  float* __restrict__ outp,
                                                  unsigned short* lds,
                                                  const int nt, const int mt, const int zz) {
    const int tid = threadIdx.x, wave = tid >> 6, lane = tid & 63;
    const int quad = lane >> 4, l16 = lane & 15;
    const int mw = (wave & 1) * 64, nw = (wave >> 1) * 64;

    f32x4 acc[4][4];
#pragma unroll
    for (int i = 0; i < 4; i++)
#pragma unroll
        for (int j = 0; j < 4; j++) acc[i][j] = (f32x4){0.f, 0.f, 0.f, 0.f};

    const unsigned short* Ab = Apk + (size_t)mt * KT * 8192;
    const unsigned short* Bb = Bpk + ((MODE == 2) ? (size_t)zz * KT * 8192 : 0)
                                   + (size_t)nt * KT * 8192;

    for (int kt = 0; kt < KT; kt++) {
        const unsigned short* as = Ab + kt * 8192 + wave * 2048 + lane * 8;
        const unsigned short* bs = Bb + kt * 8192 + wave * 2048 + lane * 8;
        unsigned short* la = lds + wave * 2048;
        unsigned short* lb = lds + 8192 + wave * 2048;
#pragma unroll
        for (int j = 0; j < 4; j++) {
            gload_lds16(as + j * 512, la + j * 512);
            gload_lds16(bs + j * 512, lb + j * 512);
        }
        __syncthreads();
#pragma unroll
        for (int kh = 0; kh < 2; kh++) {
            const int k8 = kh * 4 + quad;
            bf16x8 af[4], bfr[4];
#pragma unroll
            for (int i = 0; i < 4; i++) {
                af[i]  = *(const bf16x8*)&lds[(size_t)(k8 * 128 + mw + i * 16 + l16) * 8];
                bfr[i] = *(const bf16x8*)&lds[8192 + (size_t)(k8 * 128 + nw + i * 16 + l16) * 8];
            }
#pragma unroll
            for (int mi = 0; mi < 4; mi++)
#pragma unroll
                for (int ni = 0; ni < 4; ni++)
                    acc[mi][ni] = __builtin_amdgcn_mfma_f32_16x16x32_bf16(
                        af[mi], bfr[ni], acc[mi][ni], 0, 0, 0);
        }
        __syncthreads();
    }

    const int gm0 = mt * 128 + mw;
    const int gn0 = nt * 128 + nw;

    if (MODE == 1) {
        const int b = gn0 >> 10, t0 = gn0 & 1023;
#pragma unroll
        for (int mi = 0; mi < 4; mi++) {
#pragma unroll
            for (int r = 0; r < 4; r++) {
                const int m = gm0 + mi * 16 + quad * 4 + r;
                const float bv = bias[m];
                const size_t rowb = ((size_t)(b * C_ + m) << 10) + t0;
#pragma unroll
                for (int ni = 0; ni < 4; ni++) {
                    const size_t a = rowb + ni * 16 + l16;
                    outp[a] = acc[mi][ni][r] + bv + resid[a];
                }
            }
        }
        return;
    }

    // regions are block-uniform (128-tile never straddles a 512 boundary)
    const int region = gm0 >> 9;              // MODE0: 0=Q 1=K 2=V ; MODE2: 0=Kc 1=Vc
    const int h = (gm0 & 511) >> 6;
    const int b = (MODE == 2) ? zz : (gn0 >> 10);
    const int bh = b * 8 + h;
    const bool vregion = (MODE == 0) ? (region == 2) : (region == 1);

    if (!vregion) {
        // LDS-free packed-chunk writes for Q / K / Kc
        const float sc = (MODE == 0 && region == 0) ? QSC : 1.0f;
        unsigned short* base;
        int trow0;                            // token row base within stile, t64 base
        if (MODE == 0) {
            base = (region == 0) ? qpk + (size_t)bh * 16 * 4096
                                 : kpk + (size_t)bh * 18 * 4096;
            trow0 = gn0 & 1023;
        } else {
            base = kpk + (size_t)(bh * 18 + 16 + (gn0 >> 6)) * 4096;
            trow0 = -1;
        }
#pragma unroll
        for (int mi = 0; mi < 4; mi++) {
            const int k8 = mi * 2 + (quad >> 1);
            const int sub = (quad & 1) * 4;
#pragma unroll
            for (int ni = 0; ni < 4; ni++) {
                float vv[4];
                bool valid = true;
                if (MODE == 2) valid = (gn0 + ni * 16 + l16) < L_;
#pragma unroll
                for (int r = 0; r < 4; r++)
                    vv[r] = valid ? (acc[mi][ni][r] + bias[gm0 + mi * 16 + quad * 4 + r]) * sc
                                  : 0.f;
                uint2 d;
                d.x = pk_bf16(vv[0], vv[1]);
                d.y = pk_bf16(vv[2], vv[3]);
                unsigned short* dst;
                if (MODE == 0) {
                    const int t = trow0 + ni * 16 + l16;
                    dst = base + (size_t)(t >> 6) * 4096 + ((size_t)k8 * 64 + (t & 63)) * 8 + sub;
                } else {
                    const int row = ni * 16 + l16;
                    dst = base + ((size_t)k8 * 64 + row) * 8 + sub;
                }
                *(uint2*)dst = d;
            }
        }
    } else {
        // V: LDS transpose then chunk stores (chunks are 8 s-values per ch)
        unsigned short* wlds = lds + wave * 4608;   // 64 ch x 72
#pragma unroll
        for (int mi = 0; mi < 4; mi++)
#pragma unroll
            for (int ni = 0; ni < 4; ni++) {
                bool valid = true;
                if (MODE == 2) valid = (gn0 + ni * 16 + l16) < L_;
#pragma unroll
                for (int r = 0; r < 4; r++) {
                    const float v = valid ? acc[mi][ni][r] + bias[gm0 + mi * 16 + quad * 4 + r]
                                          : 0.f;
                    wlds[(mi * 16 + quad * 4 + r) * SROW + ni * 16 + l16] = f2bf(v);
                }
            }
        __syncthreads();
        const int stile = (MODE == 0) ? ((gn0 & 1023) >> 6) : (16 + (gn0 >> 6));
        unsigned short* dst = vpk + (size_t)(bh * 18 + stile) * 4096;
        const int sk8 = lane & 7, cb = lane >> 3;
#pragma unroll
        for (int it = 0; it < 8; it++) {
            const int ch = it * 8 + cb;
            *(uint4*)&dst[((size_t)sk8 * 64 + ch) * 8] =
                *(const uint4*)&wlds[ch * SROW + sk8 * 8];
        }
    }
}

// qkv (y=0..11) + cross (y=12, 128 blocks = 8 mt x 16 batch) fused in one dispatch:
// cross alone ran at 0.5 blocks/CU (~pure serial region); now hidden under qkv.
__global__ __launch_bounds__(256) void mgemm_qkvc_k(const unsigned short* __restrict__ wqkv_pk,
                                                    const unsigned short* __restrict__ xnT,
                                                    const float* __restrict__ b_qkv,
                                                    const unsigned short* __restrict__ wc_pk,
                                                    const unsigned short* __restrict__ cpk,
                                                    const float* __restrict__ b_c,
                                                    unsigned short* __restrict__ qpk,
                                                    unsigned short* __restrict__ kpk,
                                                    unsigned short* __restrict__ vpk) {
    __shared__ unsigned short lds[18432];   // staging A[0,8192) B[8192,16384); V-epi 4x4608
    if (blockIdx.y < 12) {
        mgemm_body<0, 8>(wqkv_pk, xnT, b_qkv, nullptr, qpk, kpk, vpk, nullptr,
                         lds, blockIdx.x, blockIdx.y, 0);
    } else {
        mgemm_body<2, 12>(wc_pk, cpk, b_c, nullptr, nullptr, kpk, vpk, nullptr,
                          lds, 0, blockIdx.x & 7, blockIdx.x >> 3);
    }
}

__global__ __launch_bounds__(256) void mgemm_proj_k(const unsigned short* __restrict__ Apk,
                                                    const unsigned short* __restrict__ Bpk,
                                                    const float* __restrict__ bias,
                                                    const float* __restrict__ resid,
                                                    float* __restrict__ outp) {
    __shared__ unsigned short lds[18432];
    mgemm_body<1, 8>(Apk, Bpk, bias, resid, nullptr, nullptr, nullptr, outp,
                     lds, blockIdx.x, blockIdx.y, 0);
}

// ---------------- Flash attention (swapped QK^T, exp2, P in-register, MFMA row-sum) -------
// Grid (bh=128, qt=8). Block: 128 q-tokens, 4 waves x 32 rows (2 B-frag sets).
// R14/R15 lesson: single-barrier K/V dbuf intermittently corrupts under graph replay;
// the TWO-barrier stile loop (stage-early -> compute -> barrier -> barrier) is the
// verified-safe structure (R15: tripwire pass, flash 67 µs).
// R16: s_setprio(1) around the MFMA clusters — blocks are phase-diverse at 4/CU
// (m191 regime: attn +4-7%); pure scheduler hint, no ordering/numerics impact.
__global__ __launch_bounds__(256, 4) void flash_k(const unsigned short* __restrict__ qpk,
                                                  const unsigned short* __restrict__ kpk,
                                                  const unsigned short* __restrict__ vpk,
                                                  unsigned short* __restrict__ aT) {
    __shared__ __align__(16) unsigned short smem[16384];  // K dbuf [0,8192) V dbuf [8192,16384)

    const int tid  = threadIdx.x;
    const int wave = tid >> 6, lane = tid & 63;
    const int quad = lane >> 4, l16 = lane & 15;
    const int bh  = blockIdx.x;
    const int b = bh >> 3, h = bh & 7;
    const int qt0 = blockIdx.y * 128;

    // Q B-frags for two 16-row sets; wave's tokens = qt0 + wave*32 + set*16 + l16
    const unsigned short* qtb = qpk + ((size_t)bh * 16 + blockIdx.y * 2 + (wave >> 1)) * 4096;
    const int qr0 = (wave & 1) * 32 + l16;
    bf16x8 bq0[2], bq1[2];
#pragma unroll
    for (int s = 0; s < 2; s++) {
        bq0[s] = *(const bf16x8*)&qtb[((size_t)quad * 64 + qr0 + s * 16) * 8];
        bq1[s] = *(const bf16x8*)&qtb[((size_t)(quad + 4) * 64 + qr0 + s * 16) * 8];
    }

    // all-ones bf16 B-fragment for the row-sum MFMA
    union { u32x4 u; bf16x8 v; } one_u;
    one_u.u = (u32x4){0x3F803F80u, 0x3F803F80u, 0x3F803F80u, 0x3F803F80u};
    const bf16x8 vones = one_u.v;

    const unsigned short* kbase = kpk + (size_t)bh * 18 * 4096 + wave * 1024 + lane * 8;
    const unsigned short* vbase = vpk + (size_t)bh * 18 * 4096 + wave * 1024 + lane * 8;

#define STAGE(p, t) do {                                                  \
        const unsigned short* kg = kbase + (size_t)(t) * 4096;            \
        const unsigned short* vg = vbase + (size_t)(t) * 4096;            \
        unsigned short* lkp = smem + (p) * 4096 + wave * 1024;            \
        unsigned short* lvp = smem + 8192 + (p) * 4096 + wave * 1024;     \
        gload_lds16(kg, lkp);       gload_lds16(kg + 512, lkp + 512);     \
        gload_lds16(vg, lvp);       gload_lds16(vg + 512, lvp + 512);     \
    } while (0)

    f32x4 l_acc[2];
    f32x4 o_acc[2][4];
#pragma unroll
    for (int s = 0; s < 2; s++) {
        l_acc[s] = (f32x4){0.f, 0.f, 0.f, 0.f};
#pragma unroll
        for (int nb = 0; nb < 4; nb++) o_acc[s][nb] = (f32x4){0.f, 0.f, 0.f, 0.f};
    }

    STAGE(0, 0);
    __syncthreads();

    for (int t = 0; t < 18; t++) {
        const int p = t & 1;
        if (t < 17) STAGE(p ^ 1, t + 1);   // issued BEFORE compute: latency covered
        const unsigned short* kb = smem + p * 4096;
        const unsigned short* vb = smem + 8192 + p * 4096;

        // QK^T: A = K rows (sb*16+l16), B = Q -> sacc[s][sb] = S[t=l16][s=sb*16+quad*4+r]
        f32x4 sacc[2][4];
        __builtin_amdgcn_s_setprio(1);
#pragma unroll
        for (int sb = 0; sb < 4; sb++) {
            const bf16x8 ak0 = *(const bf16x8*)&kb[((size_t)quad * 64 + sb * 16 + l16) * 8];
            const bf16x8 ak1 = *(const bf16x8*)&kb[((size_t)(quad + 4) * 64 + sb * 16 + l16) * 8];
#pragma unroll
            for (int s = 0; s < 2; s++) {
                f32x4 z = (f32x4){0.f, 0.f, 0.f, 0.f};
                z = __builtin_amdgcn_mfma_f32_16x16x32_bf16(ak0, bq0[s], z, 0, 0, 0);
                z = __builtin_amdgcn_mfma_f32_16x16x32_bf16(ak1, bq1[s], z, 0, 0, 0);
                sacc[s][sb] = z;
            }
        }
        __builtin_amdgcn_s_setprio(0);

        // softmax numerator + in-register transpose to PV-A layout.
        bf16x8 ap0[2], ap1[2];
#pragma unroll
        for (int s = 0; s < 2; s++) {
            unsigned w[4][2];
#pragma unroll
            for (int sb = 0; sb < 4; sb++) {
                const float e0 = exp2a(sacc[s][sb][0]);
                const float e1 = exp2a(sacc[s][sb][1]);
                const float e2 = exp2a(sacc[s][sb][2]);
                const float e3 = exp2a(sacc[s][sb][3]);
                w[sb][0] = pk_bf16(e0, e1);
                w[sb][1] = pk_bf16(e2, e3);
            }
            swap32(w[0][0], w[1][0]); swap16(w[0][0], w[1][0]);   // -> P(j0), Q(j0)
            swap32(w[0][1], w[1][1]); swap16(w[0][1], w[1][1]);   // -> P(j1), Q(j1)
            swap32(w[2][0], w[3][0]); swap16(w[2][0], w[3][0]);   // -> R(j0), S(j0)
            swap32(w[2][1], w[3][1]); swap16(w[2][1], w[3][1]);   // -> R(j1), S(j1)
            union { u32x4 u; bf16x8 v; } c0, c1;
            c0.u = (u32x4){w[0][0], w[0][1], w[1][0], w[1][1]};
            c1.u = (u32x4){w[2][0], w[2][1], w[3][0], w[3][1]};
            ap0[s] = c0.v;
            ap1[s] = c1.v;
            // row-sum on the MFMA pipe: lane(q,l) receives l[t=q*4+r] in l_acc[s][r]
            l_acc[s] = __builtin_amdgcn_mfma_f32_16x16x32_bf16(ap0[s], vones, l_acc[s], 0, 0, 0);
            l_acc[s] = __builtin_amdgcn_mfma_f32_16x16x32_bf16(ap1[s], vones, l_acc[s], 0, 0, 0);
        }

        // PV: A = P rows (in-register), B = V chunks; each bv frag feeds both row-sets
        __builtin_amdgcn_s_setprio(1);
#pragma unroll
        for (int nb = 0; nb < 4; nb++) {
            const bf16x8 bv0 = *(const bf16x8*)&vb[((size_t)quad * 64 + nb * 16 + l16) * 8];
            const bf16x8 bv1 = *(const bf16x8*)&vb[((size_t)(quad + 4) * 64 + nb * 16 + l16) * 8];
#pragma unroll
            for (int s = 0; s < 2; s++) {
                o_acc[s][nb] = __builtin_amdgcn_mfma_f32_16x16x32_bf16(ap0[s], bv0, o_acc[s][nb], 0, 0, 0);
                o_acc[s][nb] = __builtin_amdgcn_mfma_f32_16x16x32_bf16(ap1[s], bv1, o_acc[s][nb], 0, 0, 0);
            }
        }
        __builtin_amdgcn_s_setprio(0);
        __syncthreads();   // drain t+1 loads (covered by the compute above)
        __syncthreads();   // conservative ordering: no wave may touch buf p^1 until
                           // every wave has passed the post-compute drain (R14 race fix)
    }
#undef STAGE

    // l for local row quad*4+r is already in l_acc[s][r]; correct for pad tokens
    float linv[2][4];
#pragma unroll
    for (int s = 0; s < 2; s++)
#pragma unroll
        for (int r = 0; r < 4; r++)
            linv[s][r] = 1.0f / (l_acc[s][r] - (float)NPAD);

    // epilogue: O[t=s*16+quad*4+r][ch=nb*16+l16] -> stage [t][ch] in dead K/V LDS
    // -> aT packed-B chunks. Per-wave slice 32x72 shorts (9216 total <= 16384).
    unsigned short* ps = smem + wave * (32 * SROW);
#pragma unroll
    for (int s = 0; s < 2; s++)
#pragma unroll
        for (int nb = 0; nb < 4; nb++)
#pragma unroll
            for (int r = 0; r < 4; r++)
                ps[(s * 16 + quad * 4 + r) * SROW + nb * 16 + l16] =
                    f2bf(o_acc[s][nb][r] * linv[s][r]);
    asm volatile("s_waitcnt lgkmcnt(0)" ::: "memory");
    const int k8 = lane >> 3;
#pragma unroll
    for (int it = 0; it < 4; it++) {
        const int tl = (lane & 7) + it * 8;
        const int n = (b << 10) + qt0 + wave * 32 + tl;
        const int ntb = n >> 7, nm = n & 127;
        *(uint4*)&aT[(((size_t)ntb * 8 + h) * 8 + k8) * 1024 + (size_t)nm * 8] =
            *(const uint4*)&ps[tl * SROW + k8 * 8];
    }
}

// ---------------- Launch ----------------
extern "C" void kernel_launch(void* const* d_in, const int* in_sizes, int n_in,
                              void* d_out, int out_size, void* d_ws, size_t ws_size,
                              hipStream_t stream) {
    const float* x     = (const float*)d_in[0];
    const float* cin   = (const float*)d_in[1];
    const float* gamma = (const float*)d_in[2];
    const float* beta  = (const float*)d_in[3];
    const float* w_qkv = (const float*)d_in[4];
    const float* b_qkv = (const float*)d_in[5];
    const float* w_c   = (const float*)d_in[6];
    const float* b_c   = (const float*)d_in[7];
    const float* w_p   = (const float*)d_in[8];
    const float* b_p   = (const float*)d_in[9];
    float* out = (float*)d_out;

    float* ws    = (float*)d_ws;
    float* stats = ws;                                        // 1,024 f
    unsigned short* xnT     = (unsigned short*)(ws + 1024);   // 8,388,608 us
    unsigned short* wqkv_pk = xnT + 8388608;                  // 786,432 us
    unsigned short* wp_pk   = wqkv_pk + 786432;               // 262,144 us
    unsigned short* wc_pk   = wp_pk + 262144;                 // 786,432 us
    unsigned short* cpk     = wc_pk + 786432;                 // 1,572,864 us
    unsigned short* qpk     = cpk + 1572864;                  // 8,388,608 us
    unsigned short* kpk     = qpk + 8388608;                  // 9,437,184 us
    unsigned short* vpk     = kpk + 9437184;                  // 9,437,184 us
    unsigned short* aT      = vpk + 9437184;                  // 8,388,608 us
    // total ~95 MB

    prep_k<<<dim3(1600), 256, 0, stream>>>(x, stats, w_qkv, w_p, w_c, cin,
                                           wqkv_pk, wp_pk, wc_pk, cpk);
    gn_apply_t<<<dim3(16, 8, 16), 256, 0, stream>>>(x, stats, gamma, beta, xnT);
    // qkv + cross MFMA GEMMs fused -> qpk (scaled) / kpk / vpk (+stiles 16,17)
    mgemm_qkvc_k<<<dim3(128, 13), 256, 0, stream>>>(wqkv_pk, xnT, b_qkv,
                                                    wc_pk, cpk, b_c,
                                                    qpk, kpk, vpk);
    // flash attention -> aT (packed B layout for proj)
    flash_k<<<dim3(128, 8), 256, 0, stream>>>(qpk, kpk, vpk, aT);
    // proj MFMA GEMM + bias + residual -> out
    mgemm_proj_k<<<dim3(128, 4), 256, 0, stream>>>(wp_pk, aT, b_p, x, out);
}